// Round 5
// baseline (400.841 us; speedup 1.0000x reference)
//
#include <hip/hip_runtime.h>
#include <stdint.h>

#define NEGV -1.0e9f
#define EPSV 1e-12f

typedef __attribute__((ext_vector_type(8))) short bf16x8;
typedef __attribute__((ext_vector_type(4))) float f32x4;

struct __align__(8) US4 { unsigned short a, b, c, d; };

__device__ __forceinline__ unsigned int f2bf(float f) {
  unsigned int u = __builtin_bit_cast(unsigned int, f);
  u = u + 0x7FFFu + ((u >> 16) & 1u);   // round-to-nearest-even
  return u >> 16;
}

// RNE pack of two f32 -> packed bf16x2 in one VALU inst (same bits as f2bf pair;
// inputs are post-relu finite so NaN behavior is irrelevant).
__device__ __forceinline__ unsigned int cvt_pk_bf16(float lo, float hi) {
  unsigned int r;
  asm("v_cvt_pk_bf16_f32 %0, %1, %2" : "=v"(r) : "v"(lo), "v"(hi));
  return r;
}

// ---------------- k_prep: one launch, three independent jobs
__global__ __launch_bounds__(256) void k_prep(
    const float* __restrict__ state, const float* __restrict__ w1,
    const float* __restrict__ b1, const float* __restrict__ emb_w,
    const float* __restrict__ emb_b, const float* __restrict__ w2,
    float* __restrict__ W1e, float* __restrict__ sb,
    unsigned short* __restrict__ W2t) {
  const int blk = blockIdx.x;
  const int tid = threadIdx.x;
  if (blk < 4) {
    const int j = blk * 256 + tid;
    float a0 = 0.f, a1 = 0.f, a2 = 0.f, a3 = 0.f, a4 = 0.f;
    for (int e = 0; e < 256; ++e) {
      const float w = w1[(size_t)(512 + e) * 1024 + j];
      a0 += emb_w[0 * 256 + e] * w;
      a1 += emb_w[1 * 256 + e] * w;
      a2 += emb_w[2 * 256 + e] * w;
      a3 += emb_w[3 * 256 + e] * w;
      a4 += emb_w[4 * 256 + e] * w;
    }
    W1e[0 * 1024 + j] = a0;
    W1e[1 * 1024 + j] = a1;
    W1e[2 * 1024 + j] = a2;
    W1e[3 * 1024 + j] = a3;
    W1e[4 * 1024 + j] = a4;
  } else if (blk < 516) {
    const int blk2 = blk - 4;
    const int b = blk2 >> 2;
    const int j = (blk2 & 3) * 256 + tid;
    float acc = b1[j];
    for (int e = 0; e < 256; ++e)
      acc += emb_b[e] * w1[(size_t)(512 + e) * 1024 + j];
    const float* st = state + (size_t)b * 512;
    for (int s = 0; s < 512; ++s) acc += st[s] * w1[(size_t)s * 1024 + j];
    sb[(size_t)b * 1024 + j] = acc;
  } else {
    __shared__ float tile[64][65];
    const int blk2 = blk - 516;
    const int gn = blk2 & 15, gk = blk2 >> 4;
    const int c = tid & 63, w = tid >> 6;
#pragma unroll
    for (int i = 0; i < 16; ++i) {
      const int r = i * 4 + w;
      tile[r][c] = w2[(size_t)(gk * 64 + r) * 1024 + gn * 64 + c];
    }
    __syncthreads();
#pragma unroll
    for (int i = 0; i < 16; ++i) {
      const int r = i * 4 + w;
      W2t[(size_t)(gn * 64 + r) * 1024 + gk * 64 + c] = (unsigned short)f2bf(tile[c][r]);
    }
  }
}

// ---------------- k_gemm: producer/consumer fused h1+GEMM, PHASE-BARRIER schedule.
// 256x256 tile, BK=64, 12 waves: 8 consumer (2Mx4N) + 4 producer.
// R16: R2/R4 counters proved the 1-barrier/tile structure sums MFMA (2483
// cyc/SIMD) + LDS (~3000 cyc/CU) instead of overlapping (MfmaUtil pinned at
// ~35%, tweaks R1/R3/R4 all null/negative). Port of the verified 8-phase
// mechanism (T3+T4+T5, m201: 62% MfmaUtil): 4 raw s_barrier phases per K-tile.
//   consumer phase: {issue next-phase ds_reads; setprio(1); 16 MFMA;
//                    setprio(0); s_barrier}  (phases: m0-3/h0, m4-7/h0,
//                    m0-3/h1, m4-7/h1; operands always >=1 phase ahead)
//   producer:       P0 issue 8 global_load_lds + input loads (t+1);
//                   P1 rows j0-3; P2 rows j4-7; P3 vmcnt(0)+lgkmcnt(0),
//                   handoff barrier.  Raw barriers don't drain counters ->
//                   stages stay in flight across phases (T4).
// Buffers stay disjoint every phase (producer writes buf[(t+1)&1], consumers
// read buf[t&1]); barrier counts match on both paths (1 syncthreads + 64).
// Max live consumer frags = 16 (64 VGPR) — under the R1 spill cliff.
__global__ __launch_bounds__(768, 2) void k_gemm(
    const float* __restrict__ tf, const float* __restrict__ sbm,
    const float* __restrict__ W1em, const unsigned short* __restrict__ W2t,
    const float* __restrict__ b2, const float* __restrict__ w3,
    float* __restrict__ partial) {
  __shared__ unsigned short As[2][16384];   // [buf][256 rows][64 k] swizzled
  __shared__ unsigned short Bs[2][16384];

  const int bid = blockIdx.x;
  const int swz = (bid & 7) * 128 + (bid >> 3);   // XCD swizzle (1024 % 8 == 0)
  const int bx = swz >> 2, by = swz & 3;
  const int row0 = bx << 8, col0 = by << 8;
  const int bb = row0 >> 9;                       // batch (256-row tile, no straddle)

  const int tid = threadIdx.x, lane = tid & 63, wid = tid >> 6;

  if (wid < 8) {
    // ================= CONSUMER =================
    const int wr = wid >> 2, wc = wid & 3;
    const int lm = lane & 15, lg = lane >> 4;
    const int aoff = (wr * 128 + lm) * 64;        // + m*1024 + s{0,1}
    const int boff = (wc * 64 + lm) * 64;         // + n*1024 + s{0,1}
    const int s0 = ((lg ^ (lm & 7)) << 3);        // k16 = lg
    const int s1 = (((4 + lg) ^ (lm & 7)) << 3);  // k16 = 4+lg

    f32x4 acc[8][4];
#pragma unroll
    for (int m = 0; m < 8; ++m)
#pragma unroll
      for (int n = 0; n < 4; ++n) acc[m][n] = (f32x4){0.f, 0.f, 0.f, 0.f};

    __syncthreads();   // matches producer prologue (tile 0 ready)

#pragma unroll 1
    for (int t = 0; t < 16; ++t) {
      const unsigned short* Ad = As[t & 1];
      const unsigned short* Bd = Bs[t & 1];
      bf16x8 bk0[4], bk1[4], aA[4], aB[4];
      // ---- pre-tile burst: B half0 (4) + A m0-3 half0 (4)
#pragma unroll
      for (int n = 0; n < 4; ++n) bk0[n] = *(const bf16x8*)(Bd + boff + n * 1024 + s0);
#pragma unroll
      for (int m = 0; m < 4; ++m) aA[m] = *(const bf16x8*)(Ad + aoff + m * 1024 + s0);
      // ---- P0: issue A m4-7 h0; MFMA m0-3 h0
#pragma unroll
      for (int m = 0; m < 4; ++m) aB[m] = *(const bf16x8*)(Ad + aoff + (4 + m) * 1024 + s0);
      __builtin_amdgcn_s_setprio(1);
#pragma unroll
      for (int m = 0; m < 4; ++m)
#pragma unroll
        for (int n = 0; n < 4; ++n)
          acc[m][n] = __builtin_amdgcn_mfma_f32_16x16x32_bf16(aA[m], bk0[n], acc[m][n], 0, 0, 0);
      __builtin_amdgcn_s_setprio(0);
      __builtin_amdgcn_s_barrier();
      // ---- P1: issue B h1 + A m0-3 h1; MFMA m4-7 h0
#pragma unroll
      for (int n = 0; n < 4; ++n) bk1[n] = *(const bf16x8*)(Bd + boff + n * 1024 + s1);
#pragma unroll
      for (int m = 0; m < 4; ++m) aA[m] = *(const bf16x8*)(Ad + aoff + m * 1024 + s1);
      __builtin_amdgcn_s_setprio(1);
#pragma unroll
      for (int m = 0; m < 4; ++m)
#pragma unroll
        for (int n = 0; n < 4; ++n)
          acc[4 + m][n] = __builtin_amdgcn_mfma_f32_16x16x32_bf16(aB[m], bk0[n], acc[4 + m][n], 0, 0, 0);
      __builtin_amdgcn_s_setprio(0);
      __builtin_amdgcn_s_barrier();
      // ---- P2: issue A m4-7 h1; MFMA m0-3 h1
#pragma unroll
      for (int m = 0; m < 4; ++m) aB[m] = *(const bf16x8*)(Ad + aoff + (4 + m) * 1024 + s1);
      __builtin_amdgcn_s_setprio(1);
#pragma unroll
      for (int m = 0; m < 4; ++m)
#pragma unroll
        for (int n = 0; n < 4; ++n)
          acc[m][n] = __builtin_amdgcn_mfma_f32_16x16x32_bf16(aA[m], bk1[n], acc[m][n], 0, 0, 0);
      __builtin_amdgcn_s_setprio(0);
      __builtin_amdgcn_s_barrier();
      // ---- P3: MFMA m4-7 h1 (no reads; next tile's burst waits for handoff)
      __builtin_amdgcn_s_setprio(1);
#pragma unroll
      for (int m = 0; m < 4; ++m)
#pragma unroll
        for (int n = 0; n < 4; ++n)
          acc[4 + m][n] = __builtin_amdgcn_mfma_f32_16x16x32_bf16(aB[m], bk1[n], acc[4 + m][n], 0, 0, 0);
      __builtin_amdgcn_s_setprio(0);
      __builtin_amdgcn_s_barrier();   // handoff: producer drained vmcnt/lgkm before this
    }

    // ---- epilogue: partial[row][by*4+wc] = sum_cols relu(acc + b2[col]) * w3[col]
    float b2v[4], w3v[4];
#pragma unroll
    for (int n = 0; n < 4; ++n) {
      const int col = col0 + wc * 64 + n * 16 + lm;
      b2v[n] = b2[col];
      w3v[n] = w3[col];
    }
#pragma unroll
    for (int m = 0; m < 8; ++m) {
#pragma unroll
      for (int r = 0; r < 4; ++r) {
        float v = 0.f;
#pragma unroll
        for (int n = 0; n < 4; ++n) {
          float h = acc[m][n][r] + b2v[n];
          h = fmaxf(h, 0.f);
          v += h * w3v[n];
        }
        v += __shfl_xor(v, 1, 16);
        v += __shfl_xor(v, 2, 16);
        v += __shfl_xor(v, 4, 16);
        v += __shfl_xor(v, 8, 16);
        if (lm == 0)
          partial[(size_t)(row0 + wr * 128 + m * 16 + lg * 4 + r) * 16 + by * 4 + wc] = v;
      }
    }
  } else {
    // ================= PRODUCER =================
    const int pt = tid - 512;               // 0..255
    const int pw = pt >> 6;                 // producer wave 0..3
    const int pc = (pt & 7) << 3;           // 8-col block within K-tile
    const int prb = pt >> 3;                // 0..31; rows prb + 32j
    const int aph = (((pt & 7) ^ (prb & 7)) << 3);   // swizzled chunk (elems)
    // B staging: per l, row = l*32 + pw*8 + (lane>>3); pre-swizzled source col
    const int brow = (pw << 3) + (lane >> 3);
    const int bscol = (((lane & 7) ^ ((lane >> 3) & 7)) << 3);

    // tf rows -> registers (8 rows x 5)
    float ptf[8][5];
#pragma unroll
    for (int j = 0; j < 8; ++j) {
      const float* f = tf + (size_t)(row0 + prb + 32 * j) * 5;
#pragma unroll
      for (int i = 0; i < 5; ++i) ptf[j][i] = f[i];
    }

    const float* sbp = sbm + (size_t)bb * 1024;

    // h1 row block j for K-tile column block kb, into As[d] (swizzled)
#define PROD_J(j, d, sa, sbv, wa, wb)                                          \
    {                                                                          \
      const float f0 = ptf[j][0], f1 = ptf[j][1], f2 = ptf[j][2],              \
                  f3 = ptf[j][3], f4 = ptf[j][4];                              \
      float h0 = fmaf(f4, wa[4].x, fmaf(f3, wa[3].x, fmaf(f2, wa[2].x, fmaf(f1, wa[1].x, fmaf(f0, wa[0].x, sa.x))))); \
      float h1 = fmaf(f4, wa[4].y, fmaf(f3, wa[3].y, fmaf(f2, wa[2].y, fmaf(f1, wa[1].y, fmaf(f0, wa[0].y, sa.y))))); \
      float h2 = fmaf(f4, wa[4].z, fmaf(f3, wa[3].z, fmaf(f2, wa[2].z, fmaf(f1, wa[1].z, fmaf(f0, wa[0].z, sa.z))))); \
      float h3 = fmaf(f4, wa[4].w, fmaf(f3, wa[3].w, fmaf(f2, wa[2].w, fmaf(f1, wa[1].w, fmaf(f0, wa[0].w, sa.w))))); \
      float h4 = fmaf(f4, wb[4].x, fmaf(f3, wb[3].x, fmaf(f2, wb[2].x, fmaf(f1, wb[1].x, fmaf(f0, wb[0].x, sbv.x))))); \
      float h5 = fmaf(f4, wb[4].y, fmaf(f3, wb[3].y, fmaf(f2, wb[2].y, fmaf(f1, wb[1].y, fmaf(f0, wb[0].y, sbv.y))))); \
      float h6 = fmaf(f4, wb[4].z, fmaf(f3, wb[3].z, fmaf(f2, wb[2].z, fmaf(f1, wb[1].z, fmaf(f0, wb[0].z, sbv.z))))); \
      float h7 = fmaf(f4, wb[4].w, fmaf(f3, wb[3].w, fmaf(f2, wb[2].w, fmaf(f1, wb[1].w, fmaf(f0, wb[0].w, sbv.w))))); \
      h0 = fmaxf(h0, 0.f); h1 = fmaxf(h1, 0.f); h2 = fmaxf(h2, 0.f); h3 = fmaxf(h3, 0.f); \
      h4 = fmaxf(h4, 0.f); h5 = fmaxf(h5, 0.f); h6 = fmaxf(h6, 0.f); h7 = fmaxf(h7, 0.f); \
      uint4 pk;                                                                \
      pk.x = cvt_pk_bf16(h0, h1);                                              \
      pk.y = cvt_pk_bf16(h2, h3);                                              \
      pk.z = cvt_pk_bf16(h4, h5);                                              \
      pk.w = cvt_pk_bf16(h6, h7);                                              \
      *(uint4*)&As[d][(prb + 32 * (j)) * 64 + aph] = pk;                       \
    }

#define PROD_GLL(kt, d)                                                        \
    _Pragma("unroll")                                                          \
    for (int l = 0; l < 8; ++l)                                                \
      __builtin_amdgcn_global_load_lds(                                        \
          (const __attribute__((address_space(1))) void*)(                     \
              W2t + (size_t)(col0 + l * 32 + brow) * 1024 + (kt) * 64 + bscol),\
          (__attribute__((address_space(3))) void*)(                           \
              Bs[d] + (l * 32 + (pw << 3)) * 64), 16, 0, 0);

    // ---- prologue: full produce of tile 0 into buffer 0
    {
      PROD_GLL(0, 0);
      const int kb = pc;
      const float4 sa = *(const float4*)(sbp + kb);
      const float4 sbv = *(const float4*)(sbp + kb + 4);
      float4 wa[5], wb[5];
#pragma unroll
      for (int i = 0; i < 5; ++i) {
        wa[i] = *(const float4*)(W1em + i * 1024 + kb);
        wb[i] = *(const float4*)(W1em + i * 1024 + kb + 4);
      }
#pragma unroll
      for (int j = 0; j < 8; ++j) PROD_J(j, 0, sa, sbv, wa, wb);
    }
    __syncthreads();   // full drain; tile 0 ready

#pragma unroll 1
    for (int t = 0; t < 16; ++t) {
      const int kt = t + 1, d = kt & 1;
      float4 sa, sbv, wa[5], wb[5];
      // ---- P0: issue next tile's staging (stays in flight across phases)
      if (t < 15) {
        PROD_GLL(kt, d);
        const int kb = kt * 64 + pc;
        sa = *(const float4*)(sbp + kb);
        sbv = *(const float4*)(sbp + kb + 4);
#pragma unroll
        for (int i = 0; i < 5; ++i) {
          wa[i] = *(const float4*)(W1em + i * 1024 + kb);
          wb[i] = *(const float4*)(W1em + i * 1024 + kb + 4);
        }
      }
      __builtin_amdgcn_s_barrier();
      // ---- P1: h1 rows 0-3
      if (t < 15) {
#pragma unroll
        for (int j = 0; j < 4; ++j) PROD_J(j, d, sa, sbv, wa, wb);
      }
      __builtin_amdgcn_s_barrier();
      // ---- P2: h1 rows 4-7
      if (t < 15) {
#pragma unroll
        for (int j = 4; j < 8; ++j) PROD_J(j, d, sa, sbv, wa, wb);
      }
      __builtin_amdgcn_s_barrier();
      // ---- P3: drain own stages, then handoff
      asm volatile("s_waitcnt vmcnt(0) lgkmcnt(0)" ::: "memory");
      __builtin_amdgcn_s_barrier();
    }
#undef PROD_J
#undef PROD_GLL
  }
}

// ---------------- k_softmax: fused utils-reduction + nested-logit softmax
__global__ __launch_bounds__(256) void k_softmax(
    const float* __restrict__ partial, const float* __restrict__ b3,
    const int* __restrict__ nids, const int* __restrict__ mask,
    const float* __restrict__ etas, float* __restrict__ utils_out,
    float* __restrict__ p_task, float* __restrict__ p_nest) {
  const int b = blockIdx.x, tid = threadIdx.x;
  const int lane = tid & 63, wv = tid >> 6;
  __shared__ float smax[4][4];
  __shared__ int scnt[4][4];
  __shared__ float ssum[4][4];
  __shared__ float sred[4];
  __shared__ int sredi[4];

  const size_t base = (size_t)b * 512;
  const float b3v = b3[0];
  float uraw[2];
#pragma unroll
  for (int k = 0; k < 2; ++k) {
    const size_t row = base + tid + k * 256;
    const float4* p = (const float4*)(partial + row * 16);
    const float4 pa = p[0], pb = p[1], pc = p[2], pd = p[3];
    uraw[k] = b3v + pa.x + pa.y + pa.z + pa.w + pb.x + pb.y + pb.z + pb.w +
              pc.x + pc.y + pc.z + pc.w + pd.x + pd.y + pd.z + pd.w;
  }
  const int n0 = nids[base + tid], n1 = nids[base + 256 + tid];
  const bool m0 = mask[base + tid] != 0, m1 = mask[base + 256 + tid] != 0;
  const float u0 = m0 ? uraw[0] : NEGV;
  const float u1 = m1 ? uraw[1] : NEGV;
  utils_out[base + tid] = u0;
  utils_out[base + 256 + tid] = u1;
  const float eta[4] = {etas[0], etas[1], etas[2], etas[3]};

  float lmax[4]; int lcnt[4];
#pragma unroll
  for (int m = 0; m < 4; ++m) {
    const bool e0 = m0 && (n0 == m), e1 = m1 && (n1 == m);
    lmax[m] = fmaxf(e0 ? u0 : -INFINITY, e1 ? u1 : -INFINITY);
    lcnt[m] = (int)e0 + (int)e1;
  }
#pragma unroll
  for (int m = 0; m < 4; ++m)
#pragma unroll
    for (int off = 32; off >= 1; off >>= 1) {
      lmax[m] = fmaxf(lmax[m], __shfl_xor(lmax[m], off));
      lcnt[m] += __shfl_xor(lcnt[m], off);
    }
  if (lane == 0) {
#pragma unroll
    for (int m = 0; m < 4; ++m) { smax[wv][m] = lmax[m]; scnt[wv][m] = lcnt[m]; }
  }
  __syncthreads();
  float mval[4]; bool ne[4];
#pragma unroll
  for (int m = 0; m < 4; ++m) {
    const float mx = fmaxf(fmaxf(smax[0][m], smax[1][m]), fmaxf(smax[2][m], smax[3][m]));
    const int c = scnt[0][m] + scnt[1][m] + scnt[2][m] + scnt[3][m];
    ne[m] = c > 0;
    mval[m] = ne[m] ? mx : 0.f;
  }
  float lsum[4];
#pragma unroll
  for (int m = 0; m < 4; ++m) {
    float s = 0.f;
    if (m0 && n0 == m) s += expf((u0 - mval[m]) / eta[m]);
    if (m1 && n1 == m) s += expf((u1 - mval[m]) / eta[m]);
    lsum[m] = s;
  }
#pragma unroll
  for (int m = 0; m < 4; ++m)
#pragma unroll
    for (int off = 32; off >= 1; off >>= 1) lsum[m] += __shfl_xor(lsum[m], off);
  if (lane == 0) {
#pragma unroll
    for (int m = 0; m < 4; ++m) ssum[wv][m] = lsum[m];
  }
  __syncthreads();
  float sums[4], U[4];
#pragma unroll
  for (int m = 0; m < 4; ++m) {
    const float s = ssum[0][m] + ssum[1][m] + ssum[2][m] + ssum[3][m];
    sums[m] = fmaxf(s, EPSV);
    U[m] = ne[m] ? (mval[m] + eta[m] * logf(sums[m])) : NEGV;
  }
  const float mU = fmaxf(fmaxf(U[0], U[1]), fmaxf(U[2], U[3]));
  float pe[4], pes = 0.f;
#pragma unroll
  for (int m = 0; m < 4; ++m) { pe[m] = expf(U[m] - mU); pes += pe[m]; }
  float pn[4];
#pragma unroll
  for (int m = 0; m < 4; ++m) pn[m] = pe[m] / pes;
  if (tid == 0) {
#pragma unroll
    for (int m = 0; m < 4; ++m) p_nest[(size_t)b * 4 + m] = pn[m];
  }
  float pt[2];
  const float uu[2] = {u0, u1};
  const int nn[2] = {n0, n1};
  const bool mm[2] = {m0, m1};
#pragma unroll
  for (int k = 0; k < 2; ++k) {
    const bool valid = mm[k] && nn[k] >= 0 && nn[k] < 4;
    float mt = 0.f, st = 1.f, pnt = 0.f, et = 1.f;
#pragma unroll
    for (int m = 0; m < 4; ++m)
      if (nn[k] == m) { mt = mval[m]; st = sums[m]; pnt = pn[m]; et = eta[m]; }
    pt[k] = valid ? pnt * expf((uu[k] - mt) / et) / st : 0.f;
  }
  float lp = pt[0] + pt[1];
  int lmk = (int)m0 + (int)m1;
#pragma unroll
  for (int off = 32; off >= 1; off >>= 1) {
    lp += __shfl_xor(lp, off);
    lmk += __shfl_xor(lmk, off);
  }
  if (lane == 0) { sred[wv] = lp; sredi[wv] = lmk; }
  __syncthreads();
  const float sumpt = sred[0] + sred[1] + sred[2] + sred[3];
  const int nmask = sredi[0] + sredi[1] + sredi[2] + sredi[3];
  const bool fallback = (nmask > 0) && (sumpt <= EPSV);
  if (fallback) {
    const float uni = 1.f / (float)(nmask > 0 ? nmask : 1);
    pt[0] = m0 ? uni : pt[0];
    pt[1] = m1 ? uni : pt[1];
  }
  p_task[base + tid] = pt[0];
  p_task[base + 256 + tid] = pt[1];
}

extern "C" void kernel_launch(void* const* d_in, const int* in_sizes, int n_in,
                              void* d_out, int out_size, void* d_ws, size_t ws_size,
                              hipStream_t stream) {
  const float* state = (const float*)d_in[0];
  const float* tf = (const float*)d_in[1];
  const int* nids = (const int*)d_in[2];
  const int* mask = (const int*)d_in[3];
  const float* emb_w = (const float*)d_in[4];
  const float* emb_b = (const float*)d_in[5];
  const float* w1 = (const float*)d_in[6];
  const float* b1 = (const float*)d_in[7];
  const float* w2 = (const float*)d_in[8];
  const float* b2 = (const float*)d_in[9];
  const float* w3 = (const float*)d_in[10];
  const float* b3 = (const float*)d_in[11];
  const float* etas = (const float*)d_in[12];

  float* out = (float*)d_out;
  float* utils_out = out;            // 65536
  float* p_task = out + 65536;       // 65536
  float* p_nest = out + 131072;      // 512

  char* ws = (char*)d_ws;
  unsigned short* W2t = (unsigned short*)ws; ws += 1024ull * 1024 * 2;    // 2 MB
  float* partial = (float*)ws;               ws += 65536ull * 16 * 4;     // 4 MB
  float* W1e = (float*)ws;                   ws += 5 * 1024 * 4;
  float* sb = (float*)ws;                    ws += 128 * 1024 * 4;

  k_prep<<<772, 256, 0, stream>>>(state, w1, b1, emb_w, emb_b, w2, W1e, sb, W2t);
  k_gemm<<<1024, 768, 0, stream>>>(tf, sb, W1e, W2t, b2, w3, partial);
  k_softmax<<<128, 256, 0, stream>>>(partial, b3, nids, mask, etas,
                                     utils_out, p_task, p_nest);
}

// Round 6
// 400.250 us; speedup vs baseline: 1.0015x; 1.0015x over previous
//
#include <hip/hip_runtime.h>
#include <stdint.h>

#define NEGV -1.0e9f
#define EPSV 1e-12f

typedef __attribute__((ext_vector_type(8))) short bf16x8;
typedef __attribute__((ext_vector_type(4))) float f32x4;

struct __align__(8) US4 { unsigned short a, b, c, d; };

__device__ __forceinline__ unsigned int f2bf(float f) {
  unsigned int u = __builtin_bit_cast(unsigned int, f);
  u = u + 0x7FFFu + ((u >> 16) & 1u);   // round-to-nearest-even
  return u >> 16;
}

// RNE pack of two f32 -> packed bf16x2 in one VALU inst (same bits as f2bf pair;
// inputs are post-relu finite so NaN behavior is irrelevant).
__device__ __forceinline__ unsigned int cvt_pk_bf16(float lo, float hi) {
  unsigned int r;
  asm("v_cvt_pk_bf16_f32 %0, %1, %2" : "=v"(r) : "v"(lo), "v"(hi));
  return r;
}

// ---------------- k_prep: one launch, three independent jobs
__global__ __launch_bounds__(256) void k_prep(
    const float* __restrict__ state, const float* __restrict__ w1,
    const float* __restrict__ b1, const float* __restrict__ emb_w,
    const float* __restrict__ emb_b, const float* __restrict__ w2,
    float* __restrict__ W1e, float* __restrict__ sb,
    unsigned short* __restrict__ W2t) {
  const int blk = blockIdx.x;
  const int tid = threadIdx.x;
  if (blk < 4) {
    const int j = blk * 256 + tid;
    float a0 = 0.f, a1 = 0.f, a2 = 0.f, a3 = 0.f, a4 = 0.f;
    for (int e = 0; e < 256; ++e) {
      const float w = w1[(size_t)(512 + e) * 1024 + j];
      a0 += emb_w[0 * 256 + e] * w;
      a1 += emb_w[1 * 256 + e] * w;
      a2 += emb_w[2 * 256 + e] * w;
      a3 += emb_w[3 * 256 + e] * w;
      a4 += emb_w[4 * 256 + e] * w;
    }
    W1e[0 * 1024 + j] = a0;
    W1e[1 * 1024 + j] = a1;
    W1e[2 * 1024 + j] = a2;
    W1e[3 * 1024 + j] = a3;
    W1e[4 * 1024 + j] = a4;
  } else if (blk < 516) {
    const int blk2 = blk - 4;
    const int b = blk2 >> 2;
    const int j = (blk2 & 3) * 256 + tid;
    float acc = b1[j];
    for (int e = 0; e < 256; ++e)
      acc += emb_b[e] * w1[(size_t)(512 + e) * 1024 + j];
    const float* st = state + (size_t)b * 512;
    for (int s = 0; s < 512; ++s) acc += st[s] * w1[(size_t)s * 1024 + j];
    sb[(size_t)b * 1024 + j] = acc;
  } else {
    __shared__ float tile[64][65];
    const int blk2 = blk - 516;
    const int gn = blk2 & 15, gk = blk2 >> 4;
    const int c = tid & 63, w = tid >> 6;
#pragma unroll
    for (int i = 0; i < 16; ++i) {
      const int r = i * 4 + w;
      tile[r][c] = w2[(size_t)(gk * 64 + r) * 1024 + gn * 64 + c];
    }
    __syncthreads();
#pragma unroll
    for (int i = 0; i < 16; ++i) {
      const int r = i * 4 + w;
      W2t[(size_t)(gn * 64 + r) * 1024 + gk * 64 + c] = (unsigned short)f2bf(tile[c][r]);
    }
  }
}

// ---------------- k_gemm: producer/consumer fused h1+GEMM, PHASE-BARRIER schedule.
// 256x256 tile, BK=64, 12 waves: 8 consumer (2Mx4N) + 4 producer.
// REGISTER MODEL (R16 post-mortem): __launch_bounds__(768,2) made the
// allocator size arch VGPRs for a 6-waves/SIMD target (512/6 = 85) and SPILL
// anything past 84 — that killed R1 (24 frags) and R5 (16 frags + producer
// cross-barrier liveness), both at WRITE_SIZE blowups with VGPR pinned 84.
// Actual residency is 12 waves/CU (3/SIMD) in every round (AGPR 128/wave is
// kernel-wide; occupancy ~32% always). (768,1) raises the arch budget to
// ~170/wave — the phase schedule's 16-frag consumer peak and the producer's
// cross-barrier wa/wb/sa/sbv now fit with zero spill, occupancy unchanged.
// SCHEDULE (T3+T4+T5 port, verified mechanism: m201 62% MfmaUtil):
//   consumer phase: {issue next-phase ds_reads; setprio(1); 16 MFMA;
//                    setprio(0); s_barrier}  (phases: m0-3/h0, m4-7/h0,
//                    m0-3/h1, m4-7/h1; operands always >=1 phase ahead)
//   producer:       P0 issue 8 global_load_lds + input loads (t+1);
//                   P1 rows j0-3; P2 rows j4-7; P3 vmcnt(0)+lgkmcnt(0),
//                   handoff barrier.  Raw barriers don't drain counters ->
//                   stages stay in flight across phases (T4).
// Buffers disjoint every phase (producer writes buf[(t+1)&1], consumers read
// buf[t&1]); barrier counts match on both paths (1 syncthreads + 64).
__global__ __launch_bounds__(768, 1) void k_gemm(
    const float* __restrict__ tf, const float* __restrict__ sbm,
    const float* __restrict__ W1em, const unsigned short* __restrict__ W2t,
    const float* __restrict__ b2, const float* __restrict__ w3,
    float* __restrict__ partial) {
  __shared__ unsigned short As[2][16384];   // [buf][256 rows][64 k] swizzled
  __shared__ unsigned short Bs[2][16384];

  const int bid = blockIdx.x;
  const int swz = (bid & 7) * 128 + (bid >> 3);   // XCD swizzle (1024 % 8 == 0)
  const int bx = swz >> 2, by = swz & 3;
  const int row0 = bx << 8, col0 = by << 8;
  const int bb = row0 >> 9;                       // batch (256-row tile, no straddle)

  const int tid = threadIdx.x, lane = tid & 63, wid = tid >> 6;

  if (wid < 8) {
    // ================= CONSUMER =================
    const int wr = wid >> 2, wc = wid & 3;
    const int lm = lane & 15, lg = lane >> 4;
    const int aoff = (wr * 128 + lm) * 64;        // + m*1024 + s{0,1}
    const int boff = (wc * 64 + lm) * 64;         // + n*1024 + s{0,1}
    const int s0 = ((lg ^ (lm & 7)) << 3);        // k16 = lg
    const int s1 = (((4 + lg) ^ (lm & 7)) << 3);  // k16 = 4+lg

    f32x4 acc[8][4];
#pragma unroll
    for (int m = 0; m < 8; ++m)
#pragma unroll
      for (int n = 0; n < 4; ++n) acc[m][n] = (f32x4){0.f, 0.f, 0.f, 0.f};

    __syncthreads();   // matches producer prologue (tile 0 ready)

#pragma unroll 1
    for (int t = 0; t < 16; ++t) {
      const unsigned short* Ad = As[t & 1];
      const unsigned short* Bd = Bs[t & 1];
      bf16x8 bk0[4], bk1[4], aA[4], aB[4];
      // ---- pre-tile burst: B half0 (4) + A m0-3 half0 (4)
#pragma unroll
      for (int n = 0; n < 4; ++n) bk0[n] = *(const bf16x8*)(Bd + boff + n * 1024 + s0);
#pragma unroll
      for (int m = 0; m < 4; ++m) aA[m] = *(const bf16x8*)(Ad + aoff + m * 1024 + s0);
      // ---- P0: issue A m4-7 h0; MFMA m0-3 h0
#pragma unroll
      for (int m = 0; m < 4; ++m) aB[m] = *(const bf16x8*)(Ad + aoff + (4 + m) * 1024 + s0);
      __builtin_amdgcn_s_setprio(1);
#pragma unroll
      for (int m = 0; m < 4; ++m)
#pragma unroll
        for (int n = 0; n < 4; ++n)
          acc[m][n] = __builtin_amdgcn_mfma_f32_16x16x32_bf16(aA[m], bk0[n], acc[m][n], 0, 0, 0);
      __builtin_amdgcn_s_setprio(0);
      __builtin_amdgcn_s_barrier();
      // ---- P1: issue B h1 + A m0-3 h1; MFMA m4-7 h0
#pragma unroll
      for (int n = 0; n < 4; ++n) bk1[n] = *(const bf16x8*)(Bd + boff + n * 1024 + s1);
#pragma unroll
      for (int m = 0; m < 4; ++m) aA[m] = *(const bf16x8*)(Ad + aoff + m * 1024 + s1);
      __builtin_amdgcn_s_setprio(1);
#pragma unroll
      for (int m = 0; m < 4; ++m)
#pragma unroll
        for (int n = 0; n < 4; ++n)
          acc[4 + m][n] = __builtin_amdgcn_mfma_f32_16x16x32_bf16(aB[m], bk0[n], acc[4 + m][n], 0, 0, 0);
      __builtin_amdgcn_s_setprio(0);
      __builtin_amdgcn_s_barrier();
      // ---- P2: issue A m4-7 h1; MFMA m0-3 h1
#pragma unroll
      for (int m = 0; m < 4; ++m) aB[m] = *(const bf16x8*)(Ad + aoff + (4 + m) * 1024 + s1);
      __builtin_amdgcn_s_setprio(1);
#pragma unroll
      for (int m = 0; m < 4; ++m)
#pragma unroll
        for (int n = 0; n < 4; ++n)
          acc[m][n] = __builtin_amdgcn_mfma_f32_16x16x32_bf16(aA[m], bk1[n], acc[m][n], 0, 0, 0);
      __builtin_amdgcn_s_setprio(0);
      __builtin_amdgcn_s_barrier();
      // ---- P3: MFMA m4-7 h1 (no reads; next tile's burst waits for handoff)
      __builtin_amdgcn_s_setprio(1);
#pragma unroll
      for (int m = 0; m < 4; ++m)
#pragma unroll
        for (int n = 0; n < 4; ++n)
          acc[4 + m][n] = __builtin_amdgcn_mfma_f32_16x16x32_bf16(aB[m], bk1[n], acc[4 + m][n], 0, 0, 0);
      __builtin_amdgcn_s_setprio(0);
      __builtin_amdgcn_s_barrier();   // handoff: producer drained vmcnt/lgkm before this
    }

    // ---- epilogue: partial[row][by*4+wc] = sum_cols relu(acc + b2[col]) * w3[col]
    float b2v[4], w3v[4];
#pragma unroll
    for (int n = 0; n < 4; ++n) {
      const int col = col0 + wc * 64 + n * 16 + lm;
      b2v[n] = b2[col];
      w3v[n] = w3[col];
    }
#pragma unroll
    for (int m = 0; m < 8; ++m) {
#pragma unroll
      for (int r = 0; r < 4; ++r) {
        float v = 0.f;
#pragma unroll
        for (int n = 0; n < 4; ++n) {
          float h = acc[m][n][r] + b2v[n];
          h = fmaxf(h, 0.f);
          v += h * w3v[n];
        }
        v += __shfl_xor(v, 1, 16);
        v += __shfl_xor(v, 2, 16);
        v += __shfl_xor(v, 4, 16);
        v += __shfl_xor(v, 8, 16);
        if (lm == 0)
          partial[(size_t)(row0 + wr * 128 + m * 16 + lg * 4 + r) * 16 + by * 4 + wc] = v;
      }
    }
  } else {
    // ================= PRODUCER =================
    const int pt = tid - 512;               // 0..255
    const int pw = pt >> 6;                 // producer wave 0..3
    const int pc = (pt & 7) << 3;           // 8-col block within K-tile
    const int prb = pt >> 3;                // 0..31; rows prb + 32j
    const int aph = (((pt & 7) ^ (prb & 7)) << 3);   // swizzled chunk (elems)
    // B staging: per l, row = l*32 + pw*8 + (lane>>3); pre-swizzled source col
    const int brow = (pw << 3) + (lane >> 3);
    const int bscol = (((lane & 7) ^ ((lane >> 3) & 7)) << 3);

    // tf rows -> registers (8 rows x 5)
    float ptf[8][5];
#pragma unroll
    for (int j = 0; j < 8; ++j) {
      const float* f = tf + (size_t)(row0 + prb + 32 * j) * 5;
#pragma unroll
      for (int i = 0; i < 5; ++i) ptf[j][i] = f[i];
    }

    const float* sbp = sbm + (size_t)bb * 1024;

    // h1 row block j for K-tile column block kb, into As[d] (swizzled)
#define PROD_J(j, d, sa, sbv, wa, wb)                                          \
    {                                                                          \
      const float f0 = ptf[j][0], f1 = ptf[j][1], f2 = ptf[j][2],              \
                  f3 = ptf[j][3], f4 = ptf[j][4];                              \
      float h0 = fmaf(f4, wa[4].x, fmaf(f3, wa[3].x, fmaf(f2, wa[2].x, fmaf(f1, wa[1].x, fmaf(f0, wa[0].x, sa.x))))); \
      float h1 = fmaf(f4, wa[4].y, fmaf(f3, wa[3].y, fmaf(f2, wa[2].y, fmaf(f1, wa[1].y, fmaf(f0, wa[0].y, sa.y))))); \
      float h2 = fmaf(f4, wa[4].z, fmaf(f3, wa[3].z, fmaf(f2, wa[2].z, fmaf(f1, wa[1].z, fmaf(f0, wa[0].z, sa.z))))); \
      float h3 = fmaf(f4, wa[4].w, fmaf(f3, wa[3].w, fmaf(f2, wa[2].w, fmaf(f1, wa[1].w, fmaf(f0, wa[0].w, sa.w))))); \
      float h4 = fmaf(f4, wb[4].x, fmaf(f3, wb[3].x, fmaf(f2, wb[2].x, fmaf(f1, wb[1].x, fmaf(f0, wb[0].x, sbv.x))))); \
      float h5 = fmaf(f4, wb[4].y, fmaf(f3, wb[3].y, fmaf(f2, wb[2].y, fmaf(f1, wb[1].y, fmaf(f0, wb[0].y, sbv.y))))); \
      float h6 = fmaf(f4, wb[4].z, fmaf(f3, wb[3].z, fmaf(f2, wb[2].z, fmaf(f1, wb[1].z, fmaf(f0, wb[0].z, sbv.z))))); \
      float h7 = fmaf(f4, wb[4].w, fmaf(f3, wb[3].w, fmaf(f2, wb[2].w, fmaf(f1, wb[1].w, fmaf(f0, wb[0].w, sbv.w))))); \
      h0 = fmaxf(h0, 0.f); h1 = fmaxf(h1, 0.f); h2 = fmaxf(h2, 0.f); h3 = fmaxf(h3, 0.f); \
      h4 = fmaxf(h4, 0.f); h5 = fmaxf(h5, 0.f); h6 = fmaxf(h6, 0.f); h7 = fmaxf(h7, 0.f); \
      uint4 pk;                                                                \
      pk.x = cvt_pk_bf16(h0, h1);                                              \
      pk.y = cvt_pk_bf16(h2, h3);                                              \
      pk.z = cvt_pk_bf16(h4, h5);                                              \
      pk.w = cvt_pk_bf16(h6, h7);                                              \
      *(uint4*)&As[d][(prb + 32 * (j)) * 64 + aph] = pk;                       \
    }

#define PROD_GLL(kt, d)                                                        \
    _Pragma("unroll")                                                          \
    for (int l = 0; l < 8; ++l)                                                \
      __builtin_amdgcn_global_load_lds(                                        \
          (const __attribute__((address_space(1))) void*)(                     \
              W2t + (size_t)(col0 + l * 32 + brow) * 1024 + (kt) * 64 + bscol),\
          (__attribute__((address_space(3))) void*)(                           \
              Bs[d] + (l * 32 + (pw << 3)) * 64), 16, 0, 0);

    // ---- prologue: full produce of tile 0 into buffer 0
    {
      PROD_GLL(0, 0);
      const int kb = pc;
      const float4 sa = *(const float4*)(sbp + kb);
      const float4 sbv = *(const float4*)(sbp + kb + 4);
      float4 wa[5], wb[5];
#pragma unroll
      for (int i = 0; i < 5; ++i) {
        wa[i] = *(const float4*)(W1em + i * 1024 + kb);
        wb[i] = *(const float4*)(W1em + i * 1024 + kb + 4);
      }
#pragma unroll
      for (int j = 0; j < 8; ++j) PROD_J(j, 0, sa, sbv, wa, wb);
    }
    __syncthreads();   // full drain; tile 0 ready

#pragma unroll 1
    for (int t = 0; t < 16; ++t) {
      const int kt = t + 1, d = kt & 1;
      float4 sa, sbv, wa[5], wb[5];
      // ---- P0: issue next tile's staging (stays in flight across phases)
      if (t < 15) {
        PROD_GLL(kt, d);
        const int kb = kt * 64 + pc;
        sa = *(const float4*)(sbp + kb);
        sbv = *(const float4*)(sbp + kb + 4);
#pragma unroll
        for (int i = 0; i < 5; ++i) {
          wa[i] = *(const float4*)(W1em + i * 1024 + kb);
          wb[i] = *(const float4*)(W1em + i * 1024 + kb + 4);
        }
      }
      __builtin_amdgcn_s_barrier();
      // ---- P1: h1 rows 0-3
      if (t < 15) {
#pragma unroll
        for (int j = 0; j < 4; ++j) PROD_J(j, d, sa, sbv, wa, wb);
      }
      __builtin_amdgcn_s_barrier();
      // ---- P2: h1 rows 4-7
      if (t < 15) {
#pragma unroll
        for (int j = 4; j < 8; ++j) PROD_J(j, d, sa, sbv, wa, wb);
      }
      __builtin_amdgcn_s_barrier();
      // ---- P3: drain own stages, then handoff
      asm volatile("s_waitcnt vmcnt(0) lgkmcnt(0)" ::: "memory");
      __builtin_amdgcn_s_barrier();
    }
#undef PROD_J
#undef PROD_GLL
  }
}

// ---------------- k_softmax: fused utils-reduction + nested-logit softmax
__global__ __launch_bounds__(256) void k_softmax(
    const float* __restrict__ partial, const float* __restrict__ b3,
    const int* __restrict__ nids, const int* __restrict__ mask,
    const float* __restrict__ etas, float* __restrict__ utils_out,
    float* __restrict__ p_task, float* __restrict__ p_nest) {
  const int b = blockIdx.x, tid = threadIdx.x;
  const int lane = tid & 63, wv = tid >> 6;
  __shared__ float smax[4][4];
  __shared__ int scnt[4][4];
  __shared__ float ssum[4][4];
  __shared__ float sred[4];
  __shared__ int sredi[4];

  const size_t base = (size_t)b * 512;
  const float b3v = b3[0];
  float uraw[2];
#pragma unroll
  for (int k = 0; k < 2; ++k) {
    const size_t row = base + tid + k * 256;
    const float4* p = (const float4*)(partial + row * 16);
    const float4 pa = p[0], pb = p[1], pc = p[2], pd = p[3];
    uraw[k] = b3v + pa.x + pa.y + pa.z + pa.w + pb.x + pb.y + pb.z + pb.w +
              pc.x + pc.y + pc.z + pc.w + pd.x + pd.y + pd.z + pd.w;
  }
  const int n0 = nids[base + tid], n1 = nids[base + 256 + tid];
  const bool m0 = mask[base + tid] != 0, m1 = mask[base + 256 + tid] != 0;
  const float u0 = m0 ? uraw[0] : NEGV;
  const float u1 = m1 ? uraw[1] : NEGV;
  utils_out[base + tid] = u0;
  utils_out[base + 256 + tid] = u1;
  const float eta[4] = {etas[0], etas[1], etas[2], etas[3]};

  float lmax[4]; int lcnt[4];
#pragma unroll
  for (int m = 0; m < 4; ++m) {
    const bool e0 = m0 && (n0 == m), e1 = m1 && (n1 == m);
    lmax[m] = fmaxf(e0 ? u0 : -INFINITY, e1 ? u1 : -INFINITY);
    lcnt[m] = (int)e0 + (int)e1;
  }
#pragma unroll
  for (int m = 0; m < 4; ++m)
#pragma unroll
    for (int off = 32; off >= 1; off >>= 1) {
      lmax[m] = fmaxf(lmax[m], __shfl_xor(lmax[m], off));
      lcnt[m] += __shfl_xor(lcnt[m], off);
    }
  if (lane == 0) {
#pragma unroll
    for (int m = 0; m < 4; ++m) { smax[wv][m] = lmax[m]; scnt[wv][m] = lcnt[m]; }
  }
  __syncthreads();
  float mval[4]; bool ne[4];
#pragma unroll
  for (int m = 0; m < 4; ++m) {
    const float mx = fmaxf(fmaxf(smax[0][m], smax[1][m]), fmaxf(smax[2][m], smax[3][m]));
    const int c = scnt[0][m] + scnt[1][m] + scnt[2][m] + scnt[3][m];
    ne[m] = c > 0;
    mval[m] = ne[m] ? mx : 0.f;
  }
  float lsum[4];
#pragma unroll
  for (int m = 0; m < 4; ++m) {
    float s = 0.f;
    if (m0 && n0 == m) s += expf((u0 - mval[m]) / eta[m]);
    if (m1 && n1 == m) s += expf((u1 - mval[m]) / eta[m]);
    lsum[m] = s;
  }
#pragma unroll
  for (int m = 0; m < 4; ++m)
#pragma unroll
    for (int off = 32; off >= 1; off >>= 1) lsum[m] += __shfl_xor(lsum[m], off);
  if (lane == 0) {
#pragma unroll
    for (int m = 0; m < 4; ++m) ssum[wv][m] = lsum[m];
  }
  __syncthreads();
  float sums[4], U[4];
#pragma unroll
  for (int m = 0; m < 4; ++m) {
    const float s = ssum[0][m] + ssum[1][m] + ssum[2][m] + ssum[3][m];
    sums[m] = fmaxf(s, EPSV);
    U[m] = ne[m] ? (mval[m] + eta[m] * logf(sums[m])) : NEGV;
  }
  const float mU = fmaxf(fmaxf(U[0], U[1]), fmaxf(U[2], U[3]));
  float pe[4], pes = 0.f;
#pragma unroll
  for (int m = 0; m < 4; ++m) { pe[m] = expf(U[m] - mU); pes += pe[m]; }
  float pn[4];
#pragma unroll
  for (int m = 0; m < 4; ++m) pn[m] = pe[m] / pes;
  if (tid == 0) {
#pragma unroll
    for (int m = 0; m < 4; ++m) p_nest[(size_t)b * 4 + m] = pn[m];
  }
  float pt[2];
  const float uu[2] = {u0, u1};
  const int nn[2] = {n0, n1};
  const bool mm[2] = {m0, m1};
#pragma unroll
  for (int k = 0; k < 2; ++k) {
    const bool valid = mm[k] && nn[k] >= 0 && nn[k] < 4;
    float mt = 0.f, st = 1.f, pnt = 0.f, et = 1.f;
#pragma unroll
    for (int m = 0; m < 4; ++m)
      if (nn[k] == m) { mt = mval[m]; st = sums[m]; pnt = pn[m]; et = eta[m]; }
    pt[k] = valid ? pnt * expf((uu[k] - mt) / et) / st : 0.f;
  }
  float lp = pt[0] + pt[1];
  int lmk = (int)m0 + (int)m1;
#pragma unroll
  for (int off = 32; off >= 1; off >>= 1) {
    lp += __shfl_xor(lp, off);
    lmk += __shfl_xor(lmk, off);
  }
  if (lane == 0) { sred[wv] = lp; sredi[wv] = lmk; }
  __syncthreads();
  const float sumpt = sred[0] + sred[1] + sred[2] + sred[3];
  const int nmask = sredi[0] + sredi[1] + sredi[2] + sredi[3];
  const bool fallback = (nmask > 0) && (sumpt <= EPSV);
  if (fallback) {
    const float uni = 1.f / (float)(nmask > 0 ? nmask : 1);
    pt[0] = m0 ? uni : pt[0];
    pt[1] = m1 ? uni : pt[1];
  }
  p_task[base + tid] = pt[0];
  p_task[base + 256 + tid] = pt[1];
}

extern "C" void kernel_launch(void* const* d_in, const int* in_sizes, int n_in,
                              void* d_out, int out_size, void* d_ws, size_t ws_size,
                              hipStream_t stream) {
  const float* state = (const float*)d_in[0];
  const float* tf = (const float*)d_in[1];
  const int* nids = (const int*)d_in[2];
  const int* mask = (const int*)d_in[3];
  const float* emb_w = (const float*)d_in[4];
  const float* emb_b = (const float*)d_in[5];
  const float* w1 = (const float*)d_in[6];
  const float* b1 = (const float*)d_in[7];
  const float* w2 = (const float*)d_in[8];
  const float* b2 = (const float*)d_in[9];
  const float* w3 = (const float*)d_in[10];
  const float* b3 = (const float*)d_in[11];
  const float* etas = (const float*)d_in[12];

  float* out = (float*)d_out;
  float* utils_out = out;            // 65536
  float* p_task = out + 65536;       // 65536
  float* p_nest = out + 131072;      // 512

  char* ws = (char*)d_ws;
  unsigned short* W2t = (unsigned short*)ws; ws += 1024ull * 1024 * 2;    // 2 MB
  float* partial = (float*)ws;               ws += 65536ull * 16 * 4;     // 4 MB
  float* W1e = (float*)ws;                   ws += 5 * 1024 * 4;
  float* sb = (float*)ws;                    ws += 128 * 1024 * 4;

  k_prep<<<772, 256, 0, stream>>>(state, w1, b1, emb_w, emb_b, w2, W1e, sb, W2t);
  k_gemm<<<1024, 768, 0, stream>>>(tf, sb, W1e, W2t, b2, w3, partial);
  k_softmax<<<128, 256, 0, stream>>>(partial, b3, nids, mask, etas,
                                     utils_out, p_task, p_nest);
}

// Round 7
// 229.157 us; speedup vs baseline: 1.7492x; 1.7466x over previous
//
#include <hip/hip_runtime.h>
#include <stdint.h>

#define NEGV -1.0e9f
#define EPSV 1e-12f

typedef __attribute__((ext_vector_type(8))) short bf16x8;
typedef __attribute__((ext_vector_type(4))) float f32x4;

__device__ __forceinline__ unsigned int f2bf(float f) {
  unsigned int u = __builtin_bit_cast(unsigned int, f);
  u = u + 0x7FFFu + ((u >> 16) & 1u);   // round-to-nearest-even
  return u >> 16;
}

// RNE pack of two f32 -> packed bf16x2 in one VALU inst (same bits as f2bf pair;
// inputs are post-relu finite so NaN behavior is irrelevant).
__device__ __forceinline__ unsigned int cvt_pk_bf16(float lo, float hi) {
  unsigned int r;
  asm("v_cvt_pk_bf16_f32 %0, %1, %2" : "=v"(r) : "v"(lo), "v"(hi));
  return r;
}

// ---------------- k_prep: one launch, three independent jobs
__global__ __launch_bounds__(256) void k_prep(
    const float* __restrict__ state, const float* __restrict__ w1,
    const float* __restrict__ b1, const float* __restrict__ emb_w,
    const float* __restrict__ emb_b, const float* __restrict__ w2,
    float* __restrict__ W1e, float* __restrict__ sb,
    unsigned short* __restrict__ W2t) {
  const int blk = blockIdx.x;
  const int tid = threadIdx.x;
  if (blk < 4) {
    const int j = blk * 256 + tid;
    float a0 = 0.f, a1 = 0.f, a2 = 0.f, a3 = 0.f, a4 = 0.f;
    for (int e = 0; e < 256; ++e) {
      const float w = w1[(size_t)(512 + e) * 1024 + j];
      a0 += emb_w[0 * 256 + e] * w;
      a1 += emb_w[1 * 256 + e] * w;
      a2 += emb_w[2 * 256 + e] * w;
      a3 += emb_w[3 * 256 + e] * w;
      a4 += emb_w[4 * 256 + e] * w;
    }
    W1e[0 * 1024 + j] = a0;
    W1e[1 * 1024 + j] = a1;
    W1e[2 * 1024 + j] = a2;
    W1e[3 * 1024 + j] = a3;
    W1e[4 * 1024 + j] = a4;
  } else if (blk < 516) {
    const int blk2 = blk - 4;
    const int b = blk2 >> 2;
    const int j = (blk2 & 3) * 256 + tid;
    float acc = b1[j];
    for (int e = 0; e < 256; ++e)
      acc += emb_b[e] * w1[(size_t)(512 + e) * 1024 + j];
    const float* st = state + (size_t)b * 512;
    for (int s = 0; s < 512; ++s) acc += st[s] * w1[(size_t)s * 1024 + j];
    sb[(size_t)b * 1024 + j] = acc;
  } else {
    __shared__ float tile[64][65];
    const int blk2 = blk - 516;
    const int gn = blk2 & 15, gk = blk2 >> 4;
    const int c = tid & 63, w = tid >> 6;
#pragma unroll
    for (int i = 0; i < 16; ++i) {
      const int r = i * 4 + w;
      tile[r][c] = w2[(size_t)(gk * 64 + r) * 1024 + gn * 64 + c];
    }
    __syncthreads();
#pragma unroll
    for (int i = 0; i < 16; ++i) {
      const int r = i * 4 + w;
      W2t[(size_t)(gn * 64 + r) * 1024 + gk * 64 + c] = (unsigned short)f2bf(tile[c][r]);
    }
  }
}

// ---------------- k_h1: materialize H1 = relu(tf @ W1e + sb) as bf16 [65536][1024].
// Memory-bound (128 MB write). Same math+rounding as the old fused producer.
// thread: one row x 8 h-cols; writes one uint4 (coalesced 16B).
__global__ __launch_bounds__(256) void k_h1(
    const float* __restrict__ tf, const float* __restrict__ sbm,
    const float* __restrict__ W1em, unsigned short* __restrict__ H1) {
  const int tid = threadIdx.x;
  const int row = blockIdx.x * 2 + (tid >> 7);
  const int j0 = (tid & 127) << 3;
  const int b = row >> 9;
  const float* f = tf + (size_t)row * 5;
  const float f0 = f[0], f1 = f[1], f2 = f[2], f3 = f[3], f4 = f[4];
  const float* sbp = sbm + (size_t)b * 1024 + j0;
  const float4 sa = *(const float4*)(sbp);
  const float4 sbv = *(const float4*)(sbp + 4);
  float4 wa[5], wb[5];
#pragma unroll
  for (int i = 0; i < 5; ++i) {
    wa[i] = *(const float4*)(W1em + i * 1024 + j0);
    wb[i] = *(const float4*)(W1em + i * 1024 + j0 + 4);
  }
  float h0 = fmaf(f4, wa[4].x, fmaf(f3, wa[3].x, fmaf(f2, wa[2].x, fmaf(f1, wa[1].x, fmaf(f0, wa[0].x, sa.x)))));
  float h1 = fmaf(f4, wa[4].y, fmaf(f3, wa[3].y, fmaf(f2, wa[2].y, fmaf(f1, wa[1].y, fmaf(f0, wa[0].y, sa.y)))));
  float h2 = fmaf(f4, wa[4].z, fmaf(f3, wa[3].z, fmaf(f2, wa[2].z, fmaf(f1, wa[1].z, fmaf(f0, wa[0].z, sa.z)))));
  float h3 = fmaf(f4, wa[4].w, fmaf(f3, wa[3].w, fmaf(f2, wa[2].w, fmaf(f1, wa[1].w, fmaf(f0, wa[0].w, sa.w)))));
  float h4 = fmaf(f4, wb[4].x, fmaf(f3, wb[3].x, fmaf(f2, wb[2].x, fmaf(f1, wb[1].x, fmaf(f0, wb[0].x, sbv.x)))));
  float h5 = fmaf(f4, wb[4].y, fmaf(f3, wb[3].y, fmaf(f2, wb[2].y, fmaf(f1, wb[1].y, fmaf(f0, wb[0].y, sbv.y)))));
  float h6 = fmaf(f4, wb[4].z, fmaf(f3, wb[3].z, fmaf(f2, wb[2].z, fmaf(f1, wb[1].z, fmaf(f0, wb[0].z, sbv.z)))));
  float h7 = fmaf(f4, wb[4].w, fmaf(f3, wb[3].w, fmaf(f2, wb[2].w, fmaf(f1, wb[1].w, fmaf(f0, wb[0].w, sbv.w)))));
  h0 = fmaxf(h0, 0.f); h1 = fmaxf(h1, 0.f); h2 = fmaxf(h2, 0.f); h3 = fmaxf(h3, 0.f);
  h4 = fmaxf(h4, 0.f); h5 = fmaxf(h5, 0.f); h6 = fmaxf(h6, 0.f); h7 = fmaxf(h7, 0.f);
  uint4 pk;
  pk.x = cvt_pk_bf16(h0, h1);
  pk.y = cvt_pk_bf16(h2, h3);
  pk.z = cvt_pk_bf16(h4, h5);
  pk.w = cvt_pk_bf16(h6, h7);
  *(uint4*)&H1[(size_t)row * 1024 + j0] = pk;
}

// ---------------- k_gemm2: homogeneous 8-wave 256x256 GEMM (H1 @ W2t) + epilogue.
// R17: the 12-wave producer/consumer kernel is register-trapped (arch VGPR
// pinned at 84 across R0/R2/R4/R5/R6; any added liveness spills: R1/R5/R6
// WRITE_SIZE blowups). An 8-wave block (2 waves/SIMD) gets >=128 arch
// VGPR/wave under any backend occupancy target — the m201-proven operating
// point. Every wave both stages (4 A + 4 B global_load_lds/thread, swizzle-
// on-source as before) and computes (same fragment geometry, acc 128 AGPR).
// Per K-tile: issue stage(t+1) first (stays in flight across the whole tile,
// T4), 4 read-ahead ds_read/MFMA phases (reads >=16 MFMAs ahead, T3,
// setprio T5), then ONE vmcnt(0) + raw s_barrier. No intra-tile barriers
// (homogeneous waves). XCD swizzle groups the 4 N-blocks of one A-panel on
// one XCD (panel 512KB << 4MB L2) -> H1 read ~once from HBM.
__global__ __launch_bounds__(512, 2) void k_gemm2(
    const unsigned short* __restrict__ H1, const unsigned short* __restrict__ W2t,
    const float* __restrict__ b2, const float* __restrict__ w3,
    float* __restrict__ partial) {
  __shared__ unsigned short As[2][16384];   // [buf][256 rows][64 k] swizzled
  __shared__ unsigned short Bs[2][16384];

  const int bid = blockIdx.x;
  const int swz = (bid & 7) * 128 + (bid >> 3);   // XCD swizzle (1024 % 8 == 0)
  const int bx = swz >> 2, by = swz & 3;
  const int row0 = bx << 8, col0 = by << 8;

  const int tid = threadIdx.x, lane = tid & 63, wid = tid >> 6;

  // ---- staging addresses (all 8 waves stage both A and B)
  const int sr = (wid << 5) + (lane >> 3);               // tile row; + q*8
  const int scol = (((lane & 7) ^ ((lane >> 3) & 7)) << 3);  // pre-swizzled src chunk
  const size_t abase = (size_t)(row0 + sr) * 1024 + scol;
  const size_t bbase = (size_t)(col0 + sr) * 1024 + scol;
  const int ldsb = (wid << 5) * 64;                      // wave-uniform dest; + q*512

#define STAGE(kt, d)                                                          \
    _Pragma("unroll")                                                         \
    for (int q = 0; q < 4; ++q) {                                             \
      __builtin_amdgcn_global_load_lds(                                       \
          (const __attribute__((address_space(1))) void*)(                    \
              H1 + abase + (size_t)q * 8192 + (kt) * 64),                     \
          (__attribute__((address_space(3))) void*)(As[d] + ldsb + q * 512),  \
          16, 0, 0);                                                          \
      __builtin_amdgcn_global_load_lds(                                       \
          (const __attribute__((address_space(1))) void*)(                    \
              W2t + bbase + (size_t)q * 8192 + (kt) * 64),                    \
          (__attribute__((address_space(3))) void*)(Bs[d] + ldsb + q * 512),  \
          16, 0, 0);                                                          \
    }

  // ---- consumer-side constants (identical fragment geometry to before)
  const int wr = wid >> 2, wc = wid & 3;
  const int lm = lane & 15, lg = lane >> 4;
  const int aoff = (wr * 128 + lm) * 64;        // + m*1024 + s{0,1}
  const int boff = (wc * 64 + lm) * 64;         // + n*1024 + s{0,1}
  const int s0 = ((lg ^ (lm & 7)) << 3);        // k16 = lg
  const int s1 = (((4 + lg) ^ (lm & 7)) << 3);  // k16 = 4+lg

  f32x4 acc[8][4];
#pragma unroll
  for (int m = 0; m < 8; ++m)
#pragma unroll
    for (int n = 0; n < 4; ++n) acc[m][n] = (f32x4){0.f, 0.f, 0.f, 0.f};

  // ---- prologue: stage tile 0, full drain
  STAGE(0, 0);
  __syncthreads();

#pragma unroll 1
  for (int t = 0; t < 16; ++t) {
    const unsigned short* Ad = As[t & 1];
    const unsigned short* Bd = Bs[t & 1];
    // issue next tile's staging first — in flight across the whole tile (T4)
    if (t < 15) STAGE(t + 1, (t + 1) & 1);

    bf16x8 bk0[4], bk1[4], a0[4], a1[4];
    // reads for phase 0 (+1-ahead for phase 1)
#pragma unroll
    for (int n = 0; n < 4; ++n) bk0[n] = *(const bf16x8*)(Bd + boff + n * 1024 + s0);
#pragma unroll
    for (int m = 0; m < 4; ++m) a0[m] = *(const bf16x8*)(Ad + aoff + m * 1024 + s0);
#pragma unroll
    for (int m = 0; m < 4; ++m) a1[m] = *(const bf16x8*)(Ad + aoff + (4 + m) * 1024 + s0);
    __builtin_amdgcn_s_setprio(1);
#pragma unroll
    for (int m = 0; m < 4; ++m)
#pragma unroll
      for (int n = 0; n < 4; ++n)
        acc[m][n] = __builtin_amdgcn_mfma_f32_16x16x32_bf16(a0[m], bk0[n], acc[m][n], 0, 0, 0);
    __builtin_amdgcn_s_setprio(0);
    // reads for phase 2 issued before phase-1 MFMAs (>=16-MFMA distance)
#pragma unroll
    for (int n = 0; n < 4; ++n) bk1[n] = *(const bf16x8*)(Bd + boff + n * 1024 + s1);
#pragma unroll
    for (int m = 0; m < 4; ++m) a0[m] = *(const bf16x8*)(Ad + aoff + m * 1024 + s1);
    __builtin_amdgcn_s_setprio(1);
#pragma unroll
    for (int m = 0; m < 4; ++m)
#pragma unroll
      for (int n = 0; n < 4; ++n)
        acc[4 + m][n] = __builtin_amdgcn_mfma_f32_16x16x32_bf16(a1[m], bk0[n], acc[4 + m][n], 0, 0, 0);
    __builtin_amdgcn_s_setprio(0);
#pragma unroll
    for (int m = 0; m < 4; ++m) a1[m] = *(const bf16x8*)(Ad + aoff + (4 + m) * 1024 + s1);
    __builtin_amdgcn_s_setprio(1);
#pragma unroll
    for (int m = 0; m < 4; ++m)
#pragma unroll
      for (int n = 0; n < 4; ++n)
        acc[m][n] = __builtin_amdgcn_mfma_f32_16x16x32_bf16(a0[m], bk1[n], acc[m][n], 0, 0, 0);
#pragma unroll
    for (int m = 0; m < 4; ++m)
#pragma unroll
      for (int n = 0; n < 4; ++n)
        acc[4 + m][n] = __builtin_amdgcn_mfma_f32_16x16x32_bf16(a1[m], bk1[n], acc[4 + m][n], 0, 0, 0);
    __builtin_amdgcn_s_setprio(0);

    // own stage(t+1) landed; barrier = everyone's landed + done reading buf
    if (t < 15) asm volatile("s_waitcnt vmcnt(0)" ::: "memory");
    __builtin_amdgcn_s_barrier();
  }
#undef STAGE

  // ---- epilogue: partial[row][by*4+wc] = sum_cols relu(acc + b2[col]) * w3[col]
  float b2v[4], w3v[4];
#pragma unroll
  for (int n = 0; n < 4; ++n) {
    const int col = col0 + wc * 64 + n * 16 + lm;
    b2v[n] = b2[col];
    w3v[n] = w3[col];
  }
#pragma unroll
  for (int m = 0; m < 8; ++m) {
#pragma unroll
    for (int r = 0; r < 4; ++r) {
      float v = 0.f;
#pragma unroll
      for (int n = 0; n < 4; ++n) {
        float h = acc[m][n][r] + b2v[n];
        h = fmaxf(h, 0.f);
        v += h * w3v[n];
      }
      v += __shfl_xor(v, 1, 16);
      v += __shfl_xor(v, 2, 16);
      v += __shfl_xor(v, 4, 16);
      v += __shfl_xor(v, 8, 16);
      if (lm == 0)
        partial[(size_t)(row0 + wr * 128 + m * 16 + lg * 4 + r) * 16 + by * 4 + wc] = v;
    }
  }
}

// ---------------- k_softmax: fused utils-reduction + nested-logit softmax
__global__ __launch_bounds__(256) void k_softmax(
    const float* __restrict__ partial, const float* __restrict__ b3,
    const int* __restrict__ nids, const int* __restrict__ mask,
    const float* __restrict__ etas, float* __restrict__ utils_out,
    float* __restrict__ p_task, float* __restrict__ p_nest) {
  const int b = blockIdx.x, tid = threadIdx.x;
  const int lane = tid & 63, wv = tid >> 6;
  __shared__ float smax[4][4];
  __shared__ int scnt[4][4];
  __shared__ float ssum[4][4];
  __shared__ float sred[4];
  __shared__ int sredi[4];

  const size_t base = (size_t)b * 512;
  const float b3v = b3[0];
  float uraw[2];
#pragma unroll
  for (int k = 0; k < 2; ++k) {
    const size_t row = base + tid + k * 256;
    const float4* p = (const float4*)(partial + row * 16);
    const float4 pa = p[0], pb = p[1], pc = p[2], pd = p[3];
    uraw[k] = b3v + pa.x + pa.y + pa.z + pa.w + pb.x + pb.y + pb.z + pb.w +
              pc.x + pc.y + pc.z + pc.w + pd.x + pd.y + pd.z + pd.w;
  }
  const int n0 = nids[base + tid], n1 = nids[base + 256 + tid];
  const bool m0 = mask[base + tid] != 0, m1 = mask[base + 256 + tid] != 0;
  const float u0 = m0 ? uraw[0] : NEGV;
  const float u1 = m1 ? uraw[1] : NEGV;
  utils_out[base + tid] = u0;
  utils_out[base + 256 + tid] = u1;
  const float eta[4] = {etas[0], etas[1], etas[2], etas[3]};

  float lmax[4]; int lcnt[4];
#pragma unroll
  for (int m = 0; m < 4; ++m) {
    const bool e0 = m0 && (n0 == m), e1 = m1 && (n1 == m);
    lmax[m] = fmaxf(e0 ? u0 : -INFINITY, e1 ? u1 : -INFINITY);
    lcnt[m] = (int)e0 + (int)e1;
  }
#pragma unroll
  for (int m = 0; m < 4; ++m)
#pragma unroll
    for (int off = 32; off >= 1; off >>= 1) {
      lmax[m] = fmaxf(lmax[m], __shfl_xor(lmax[m], off));
      lcnt[m] += __shfl_xor(lcnt[m], off);
    }
  if (lane == 0) {
#pragma unroll
    for (int m = 0; m < 4; ++m) { smax[wv][m] = lmax[m]; scnt[wv][m] = lcnt[m]; }
  }
  __syncthreads();
  float mval[4]; bool ne[4];
#pragma unroll
  for (int m = 0; m < 4; ++m) {
    const float mx = fmaxf(fmaxf(smax[0][m], smax[1][m]), fmaxf(smax[2][m], smax[3][m]));
    const int c = scnt[0][m] + scnt[1][m] + scnt[2][m] + scnt[3][m];
    ne[m] = c > 0;
    mval[m] = ne[m] ? mx : 0.f;
  }
  float lsum[4];
#pragma unroll
  for (int m = 0; m < 4; ++m) {
    float s = 0.f;
    if (m0 && n0 == m) s += expf((u0 - mval[m]) / eta[m]);
    if (m1 && n1 == m) s += expf((u1 - mval[m]) / eta[m]);
    lsum[m] = s;
  }
#pragma unroll
  for (int m = 0; m < 4; ++m)
#pragma unroll
    for (int off = 32; off >= 1; off >>= 1) lsum[m] += __shfl_xor(lsum[m], off);
  if (lane == 0) {
#pragma unroll
    for (int m = 0; m < 4; ++m) ssum[wv][m] = lsum[m];
  }
  __syncthreads();
  float sums[4], U[4];
#pragma unroll
  for (int m = 0; m < 4; ++m) {
    const float s = ssum[0][m] + ssum[1][m] + ssum[2][m] + ssum[3][m];
    sums[m] = fmaxf(s, EPSV);
    U[m] = ne[m] ? (mval[m] + eta[m] * logf(sums[m])) : NEGV;
  }
  const float mU = fmaxf(fmaxf(U[0], U[1]), fmaxf(U[2], U[3]));
  float pe[4], pes = 0.f;
#pragma unroll
  for (int m = 0; m < 4; ++m) { pe[m] = expf(U[m] - mU); pes += pe[m]; }
  float pn[4];
#pragma unroll
  for (int m = 0; m < 4; ++m) pn[m] = pe[m] / pes;
  if (tid == 0) {
#pragma unroll
    for (int m = 0; m < 4; ++m) p_nest[(size_t)b * 4 + m] = pn[m];
  }
  float pt[2];
  const float uu[2] = {u0, u1};
  const int nn[2] = {n0, n1};
  const bool mm[2] = {m0, m1};
#pragma unroll
  for (int k = 0; k < 2; ++k) {
    const bool valid = mm[k] && nn[k] >= 0 && nn[k] < 4;
    float mt = 0.f, st = 1.f, pnt = 0.f, et = 1.f;
#pragma unroll
    for (int m = 0; m < 4; ++m)
      if (nn[k] == m) { mt = mval[m]; st = sums[m]; pnt = pn[m]; et = eta[m]; }
    pt[k] = valid ? pnt * expf((uu[k] - mt) / et) / st : 0.f;
  }
  float lp = pt[0] + pt[1];
  int lmk = (int)m0 + (int)m1;
#pragma unroll
  for (int off = 32; off >= 1; off >>= 1) {
    lp += __shfl_xor(lp, off);
    lmk += __shfl_xor(lmk, off);
  }
  if (lane == 0) { sred[wv] = lp; sredi[wv] = lmk; }
  __syncthreads();
  const float sumpt = sred[0] + sred[1] + sred[2] + sred[3];
  const int nmask = sredi[0] + sredi[1] + sredi[2] + sredi[3];
  const bool fallback = (nmask > 0) && (sumpt <= EPSV);
  if (fallback) {
    const float uni = 1.f / (float)(nmask > 0 ? nmask : 1);
    pt[0] = m0 ? uni : pt[0];
    pt[1] = m1 ? uni : pt[1];
  }
  p_task[base + tid] = pt[0];
  p_task[base + 256 + tid] = pt[1];
}

extern "C" void kernel_launch(void* const* d_in, const int* in_sizes, int n_in,
                              void* d_out, int out_size, void* d_ws, size_t ws_size,
                              hipStream_t stream) {
  const float* state = (const float*)d_in[0];
  const float* tf = (const float*)d_in[1];
  const int* nids = (const int*)d_in[2];
  const int* mask = (const int*)d_in[3];
  const float* emb_w = (const float*)d_in[4];
  const float* emb_b = (const float*)d_in[5];
  const float* w1 = (const float*)d_in[6];
  const float* b1 = (const float*)d_in[7];
  const float* w2 = (const float*)d_in[8];
  const float* b2 = (const float*)d_in[9];
  const float* w3 = (const float*)d_in[10];
  const float* b3 = (const float*)d_in[11];
  const float* etas = (const float*)d_in[12];

  float* out = (float*)d_out;
  float* utils_out = out;            // 65536
  float* p_task = out + 65536;       // 65536
  float* p_nest = out + 131072;      // 512

  char* ws = (char*)d_ws;
  unsigned short* W2t = (unsigned short*)ws; ws += 1024ull * 1024 * 2;    // 2 MB
  float* partial = (float*)ws;               ws += 65536ull * 16 * 4;     // 4 MB
  float* W1e = (float*)ws;                   ws += 5 * 1024 * 4;
  float* sb = (float*)ws;                    ws += 128 * 1024 * 4;
  unsigned short* H1 = (unsigned short*)ws;  ws += 65536ull * 1024 * 2;   // 128 MB

  k_prep<<<772, 256, 0, stream>>>(state, w1, b1, emb_w, emb_b, w2, W1e, sb, W2t);
  k_h1<<<32768, 256, 0, stream>>>(tf, sb, W1e, H1);
  k_gemm2<<<1024, 512, 0, stream>>>(H1, W2t, b2, w3, partial);
  k_softmax<<<128, 256, 0, stream>>>(partial, b3, nids, mask, etas,
                                     utils_out, p_task, p_nest);
}

// Round 8
// 188.344 us; speedup vs baseline: 2.1282x; 1.2167x over previous
//
#include <hip/hip_runtime.h>
#include <stdint.h>

#define NEGV -1.0e9f
#define EPSV 1e-12f

typedef __attribute__((ext_vector_type(8))) short bf16x8;
typedef __attribute__((ext_vector_type(4))) float f32x4;

__device__ __forceinline__ unsigned int f2bf(float f) {
  unsigned int u = __builtin_bit_cast(unsigned int, f);
  u = u + 0x7FFFu + ((u >> 16) & 1u);   // round-to-nearest-even
  return u >> 16;
}

// RNE pack of two f32 -> packed bf16x2 in one VALU inst (same bits as f2bf pair;
// inputs are post-relu finite so NaN behavior is irrelevant).
__device__ __forceinline__ unsigned int cvt_pk_bf16(float lo, float hi) {
  unsigned int r;
  asm("v_cvt_pk_bf16_f32 %0, %1, %2" : "=v"(r) : "v"(lo), "v"(hi));
  return r;
}

// ---------------- k_prep: one launch, three independent jobs
__global__ __launch_bounds__(256) void k_prep(
    const float* __restrict__ state, const float* __restrict__ w1,
    const float* __restrict__ b1, const float* __restrict__ emb_w,
    const float* __restrict__ emb_b, const float* __restrict__ w2,
    float* __restrict__ W1e, float* __restrict__ sb,
    unsigned short* __restrict__ W2t) {
  const int blk = blockIdx.x;
  const int tid = threadIdx.x;
  if (blk < 4) {
    const int j = blk * 256 + tid;
    float a0 = 0.f, a1 = 0.f, a2 = 0.f, a3 = 0.f, a4 = 0.f;
    for (int e = 0; e < 256; ++e) {
      const float w = w1[(size_t)(512 + e) * 1024 + j];
      a0 += emb_w[0 * 256 + e] * w;
      a1 += emb_w[1 * 256 + e] * w;
      a2 += emb_w[2 * 256 + e] * w;
      a3 += emb_w[3 * 256 + e] * w;
      a4 += emb_w[4 * 256 + e] * w;
    }
    W1e[0 * 1024 + j] = a0;
    W1e[1 * 1024 + j] = a1;
    W1e[2 * 1024 + j] = a2;
    W1e[3 * 1024 + j] = a3;
    W1e[4 * 1024 + j] = a4;
  } else if (blk < 516) {
    const int blk2 = blk - 4;
    const int b = blk2 >> 2;
    const int j = (blk2 & 3) * 256 + tid;
    float acc = b1[j];
    for (int e = 0; e < 256; ++e)
      acc += emb_b[e] * w1[(size_t)(512 + e) * 1024 + j];
    const float* st = state + (size_t)b * 512;
    for (int s = 0; s < 512; ++s) acc += st[s] * w1[(size_t)s * 1024 + j];
    sb[(size_t)b * 1024 + j] = acc;
  } else {
    __shared__ float tile[64][65];
    const int blk2 = blk - 516;
    const int gn = blk2 & 15, gk = blk2 >> 4;
    const int c = tid & 63, w = tid >> 6;
#pragma unroll
    for (int i = 0; i < 16; ++i) {
      const int r = i * 4 + w;
      tile[r][c] = w2[(size_t)(gk * 64 + r) * 1024 + gn * 64 + c];
    }
    __syncthreads();
#pragma unroll
    for (int i = 0; i < 16; ++i) {
      const int r = i * 4 + w;
      W2t[(size_t)(gn * 64 + r) * 1024 + gk * 64 + c] = (unsigned short)f2bf(tile[c][r]);
    }
  }
}

// ---------------- k_h1: materialize H1 = relu(tf @ W1e + sb) as bf16 [65536][1024].
// R18: R7's k_h1 ran ~50us (2x the 128MB write roofline) from 10x L2 read
// amplification (160B W1e per 16B out). Fix: 8 rows per thread — wa/wb/sa
// loaded once, reused 8x. 8-row group never straddles a batch (512-row)
// boundary. Writes stay fully coalesced (128 threads cover one 2048B row).
__global__ __launch_bounds__(256) void k_h1(
    const float* __restrict__ tf, const float* __restrict__ sbm,
    const float* __restrict__ W1em, unsigned short* __restrict__ H1) {
  const int tid = threadIdx.x;
  const int j0 = (tid & 127) << 3;
  const int r0 = (blockIdx.x * 2 + (tid >> 7)) * 8;   // 8 rows per thread
  const int b = r0 >> 9;
  const float* sbp = sbm + (size_t)b * 1024 + j0;
  const float4 sa = *(const float4*)(sbp);
  const float4 sbv = *(const float4*)(sbp + 4);
  float4 wa[5], wb[5];
#pragma unroll
  for (int i = 0; i < 5; ++i) {
    wa[i] = *(const float4*)(W1em + i * 1024 + j0);
    wb[i] = *(const float4*)(W1em + i * 1024 + j0 + 4);
  }
#pragma unroll
  for (int r = 0; r < 8; ++r) {
    const float* f = tf + (size_t)(r0 + r) * 5;
    const float f0 = f[0], f1 = f[1], f2 = f[2], f3 = f[3], f4 = f[4];
    float h0 = fmaf(f4, wa[4].x, fmaf(f3, wa[3].x, fmaf(f2, wa[2].x, fmaf(f1, wa[1].x, fmaf(f0, wa[0].x, sa.x)))));
    float h1 = fmaf(f4, wa[4].y, fmaf(f3, wa[3].y, fmaf(f2, wa[2].y, fmaf(f1, wa[1].y, fmaf(f0, wa[0].y, sa.y)))));
    float h2 = fmaf(f4, wa[4].z, fmaf(f3, wa[3].z, fmaf(f2, wa[2].z, fmaf(f1, wa[1].z, fmaf(f0, wa[0].z, sa.z)))));
    float h3 = fmaf(f4, wa[4].w, fmaf(f3, wa[3].w, fmaf(f2, wa[2].w, fmaf(f1, wa[1].w, fmaf(f0, wa[0].w, sa.w)))));
    float h4 = fmaf(f4, wb[4].x, fmaf(f3, wb[3].x, fmaf(f2, wb[2].x, fmaf(f1, wb[1].x, fmaf(f0, wb[0].x, sbv.x)))));
    float h5 = fmaf(f4, wb[4].y, fmaf(f3, wb[3].y, fmaf(f2, wb[2].y, fmaf(f1, wb[1].y, fmaf(f0, wb[0].y, sbv.y)))));
    float h6 = fmaf(f4, wb[4].z, fmaf(f3, wb[3].z, fmaf(f2, wb[2].z, fmaf(f1, wb[1].z, fmaf(f0, wb[0].z, sbv.z)))));
    float h7 = fmaf(f4, wb[4].w, fmaf(f3, wb[3].w, fmaf(f2, wb[2].w, fmaf(f1, wb[1].w, fmaf(f0, wb[0].w, sbv.w)))));
    h0 = fmaxf(h0, 0.f); h1 = fmaxf(h1, 0.f); h2 = fmaxf(h2, 0.f); h3 = fmaxf(h3, 0.f);
    h4 = fmaxf(h4, 0.f); h5 = fmaxf(h5, 0.f); h6 = fmaxf(h6, 0.f); h7 = fmaxf(h7, 0.f);
    uint4 pk;
    pk.x = cvt_pk_bf16(h0, h1);
    pk.y = cvt_pk_bf16(h2, h3);
    pk.z = cvt_pk_bf16(h4, h5);
    pk.w = cvt_pk_bf16(h6, h7);
    *(uint4*)&H1[(size_t)(r0 + r) * 1024 + j0] = pk;
  }
}

// ---------------- k_gemm2: homogeneous 8-wave 256x256 GEMM (H1 @ W2t) + epilogue.
// R18: R7 (reads hoisted, ONE barrier/tile) landed at 877 TF / MfmaUtil 37% —
// exactly the documented m97-structure ceiling (874-912 TF, 37%). The
// verified escape (m201: 1563 TF, 62%) is the per-phase barrier-pair:
//   phase = { ds_reads (this phase's frags); 2x global_load_lds (spread);
//             s_barrier; lgkmcnt(0)+sched_barrier(0) [rule #18];
//             setprio(1); 16 MFMA; setprio(0); s_barrier }
// 4 phases per K-tile (m-pair decomposition: phase p = rows {2p,2p+1} x 4n x
// K=64). B-frags (8) read at p0, live all tile; A-frags 4/phase. Peak ~16
// frags -> arch VGPR must stay <=128 so arch+128 AGPR <= 256 and 2 waves/SIMD
// survive (hard constraint; WRITE_SIZE=4096KB is the no-spill sentinel).
// vmcnt(0) for own 8 stage loads only at p3 (drain had >=3 phases to land).
__global__ __launch_bounds__(512, 2) void k_gemm2(
    const unsigned short* __restrict__ H1, const unsigned short* __restrict__ W2t,
    const float* __restrict__ b2, const float* __restrict__ w3,
    float* __restrict__ partial) {
  __shared__ unsigned short As[2][16384];   // [buf][256 rows][64 k] swizzled
  __shared__ unsigned short Bs[2][16384];

  const int bid = blockIdx.x;
  const int swz = (bid & 7) * 128 + (bid >> 3);   // XCD swizzle (1024 % 8 == 0)
  const int bx = swz >> 2, by = swz & 3;
  const int row0 = bx << 8, col0 = by << 8;

  const int tid = threadIdx.x, lane = tid & 63, wid = tid >> 6;

  // ---- staging addresses (all 8 waves stage both A and B)
  const int sr = (wid << 5) + (lane >> 3);               // tile row; + q*8
  const int scol = (((lane & 7) ^ ((lane >> 3) & 7)) << 3);  // pre-swizzled src chunk
  const size_t abase = (size_t)(row0 + sr) * 1024 + scol;
  const size_t bbase = (size_t)(col0 + sr) * 1024 + scol;
  const int ldsb = (wid << 5) * 64;                      // wave-uniform dest; + q*512

#define STAGE8(kt, d)                                                         \
    _Pragma("unroll")                                                         \
    for (int q = 0; q < 4; ++q) {                                             \
      __builtin_amdgcn_global_load_lds(                                       \
          (const __attribute__((address_space(1))) void*)(                    \
              H1 + abase + (size_t)q * 8192 + (kt) * 64),                     \
          (__attribute__((address_space(3))) void*)(As[d] + ldsb + q * 512),  \
          16, 0, 0);                                                          \
      __builtin_amdgcn_global_load_lds(                                       \
          (const __attribute__((address_space(1))) void*)(                    \
              W2t + bbase + (size_t)q * 8192 + (kt) * 64),                    \
          (__attribute__((address_space(3))) void*)(Bs[d] + ldsb + q * 512),  \
          16, 0, 0);                                                          \
    }

#define STAGE2(kt, d, q)                                                      \
    {                                                                         \
      __builtin_amdgcn_global_load_lds(                                       \
          (const __attribute__((address_space(1))) void*)(                    \
              H1 + abase + (size_t)(q) * 8192 + (kt) * 64),                   \
          (__attribute__((address_space(3))) void*)(As[d] + ldsb + (q) * 512),\
          16, 0, 0);                                                          \
      __builtin_amdgcn_global_load_lds(                                       \
          (const __attribute__((address_space(1))) void*)(                    \
              W2t + bbase + (size_t)(q) * 8192 + (kt) * 64),                  \
          (__attribute__((address_space(3))) void*)(Bs[d] + ldsb + (q) * 512),\
          16, 0, 0);                                                          \
    }

  // ---- consumer-side constants (identical fragment geometry to R7)
  const int wr = wid >> 2, wc = wid & 3;
  const int lm = lane & 15, lg = lane >> 4;
  const int aoff = (wr * 128 + lm) * 64;        // + m*1024 + s{0,1}
  const int boff = (wc * 64 + lm) * 64;         // + n*1024 + s{0,1}
  const int s0 = ((lg ^ (lm & 7)) << 3);        // k16 = lg
  const int s1 = (((4 + lg) ^ (lm & 7)) << 3);  // k16 = 4+lg

  f32x4 acc[8][4];
#pragma unroll
  for (int m = 0; m < 8; ++m)
#pragma unroll
    for (int n = 0; n < 4; ++n) acc[m][n] = (f32x4){0.f, 0.f, 0.f, 0.f};

  // ---- prologue: stage tile 0, full drain
  STAGE8(0, 0);
  __syncthreads();

#pragma unroll 1
  for (int t = 0; t < 16; ++t) {
    const unsigned short* Ad = As[t & 1];
    const unsigned short* Bd = Bs[t & 1];
    bf16x8 bk0[4], bk1[4];
#pragma unroll
    for (int p = 0; p < 4; ++p) {
      // ---- this phase's ds_reads
      if (p == 0) {
#pragma unroll
        for (int n = 0; n < 4; ++n) {
          bk0[n] = *(const bf16x8*)(Bd + boff + n * 1024 + s0);
          bk1[n] = *(const bf16x8*)(Bd + boff + n * 1024 + s1);
        }
      }
      bf16x8 a0k0 = *(const bf16x8*)(Ad + aoff + (2 * p) * 1024 + s0);
      bf16x8 a0k1 = *(const bf16x8*)(Ad + aoff + (2 * p) * 1024 + s1);
      bf16x8 a1k0 = *(const bf16x8*)(Ad + aoff + (2 * p + 1) * 1024 + s0);
      bf16x8 a1k1 = *(const bf16x8*)(Ad + aoff + (2 * p + 1) * 1024 + s1);
      // ---- spread staging: 2 of 8 loads per phase (in flight across barriers)
      if (t < 15) STAGE2(t + 1, (t + 1) & 1, p);
      __builtin_amdgcn_s_barrier();
      asm volatile("s_waitcnt lgkmcnt(0)" ::: "memory");
      __builtin_amdgcn_sched_barrier(0);
      __builtin_amdgcn_s_setprio(1);
#pragma unroll
      for (int n = 0; n < 4; ++n)
        acc[2 * p][n] = __builtin_amdgcn_mfma_f32_16x16x32_bf16(a0k0, bk0[n], acc[2 * p][n], 0, 0, 0);
#pragma unroll
      for (int n = 0; n < 4; ++n)
        acc[2 * p][n] = __builtin_amdgcn_mfma_f32_16x16x32_bf16(a0k1, bk1[n], acc[2 * p][n], 0, 0, 0);
#pragma unroll
      for (int n = 0; n < 4; ++n)
        acc[2 * p + 1][n] = __builtin_amdgcn_mfma_f32_16x16x32_bf16(a1k0, bk0[n], acc[2 * p + 1][n], 0, 0, 0);
#pragma unroll
      for (int n = 0; n < 4; ++n)
        acc[2 * p + 1][n] = __builtin_amdgcn_mfma_f32_16x16x32_bf16(a1k1, bk1[n], acc[2 * p + 1][n], 0, 0, 0);
      __builtin_amdgcn_s_setprio(0);
      // ---- tile end: drain own 8 stage loads (issued >=1..4 phases ago)
      if (p == 3 && t < 15) asm volatile("s_waitcnt vmcnt(0)" ::: "memory");
      __builtin_amdgcn_s_barrier();
    }
  }
#undef STAGE8
#undef STAGE2

  // ---- epilogue: partial[row][by*4+wc] = sum_cols relu(acc + b2[col]) * w3[col]
  float b2v[4], w3v[4];
#pragma unroll
  for (int n = 0; n < 4; ++n) {
    const int col = col0 + wc * 64 + n * 16 + lm;
    b2v[n] = b2[col];
    w3v[n] = w3[col];
  }
#pragma unroll
  for (int m = 0; m < 8; ++m) {
#pragma unroll
    for (int r = 0; r < 4; ++r) {
      float v = 0.f;
#pragma unroll
      for (int n = 0; n < 4; ++n) {
        float h = acc[m][n][r] + b2v[n];
        h = fmaxf(h, 0.f);
        v += h * w3v[n];
      }
      v += __shfl_xor(v, 1, 16);
      v += __shfl_xor(v, 2, 16);
      v += __shfl_xor(v, 4, 16);
      v += __shfl_xor(v, 8, 16);
      if (lm == 0)
        partial[(size_t)(row0 + wr * 128 + m * 16 + lg * 4 + r) * 16 + by * 4 + wc] = v;
    }
  }
}

// ---------------- k_softmax: fused utils-reduction + nested-logit softmax
__global__ __launch_bounds__(256) void k_softmax(
    const float* __restrict__ partial, const float* __restrict__ b3,
    const int* __restrict__ nids, const int* __restrict__ mask,
    const float* __restrict__ etas, float* __restrict__ utils_out,
    float* __restrict__ p_task, float* __restrict__ p_nest) {
  const int b = blockIdx.x, tid = threadIdx.x;
  const int lane = tid & 63, wv = tid >> 6;
  __shared__ float smax[4][4];
  __shared__ int scnt[4][4];
  __shared__ float ssum[4][4];
  __shared__ float sred[4];
  __shared__ int sredi[4];

  const size_t base = (size_t)b * 512;
  const float b3v = b3[0];
  float uraw[2];
#pragma unroll
  for (int k = 0; k < 2; ++k) {
    const size_t row = base + tid + k * 256;
    const float4* p = (const float4*)(partial + row * 16);
    const float4 pa = p[0], pb = p[1], pc = p[2], pd = p[3];
    uraw[k] = b3v + pa.x + pa.y + pa.z + pa.w + pb.x + pb.y + pb.z + pb.w +
              pc.x + pc.y + pc.z + pc.w + pd.x + pd.y + pd.z + pd.w;
  }
  const int n0 = nids[base + tid], n1 = nids[base + 256 + tid];
  const bool m0 = mask[base + tid] != 0, m1 = mask[base + 256 + tid] != 0;
  const float u0 = m0 ? uraw[0] : NEGV;
  const float u1 = m1 ? uraw[1] : NEGV;
  utils_out[base + tid] = u0;
  utils_out[base + 256 + tid] = u1;
  const float eta[4] = {etas[0], etas[1], etas[2], etas[3]};

  float lmax[4]; int lcnt[4];
#pragma unroll
  for (int m = 0; m < 4; ++m) {
    const bool e0 = m0 && (n0 == m), e1 = m1 && (n1 == m);
    lmax[m] = fmaxf(e0 ? u0 : -INFINITY, e1 ? u1 : -INFINITY);
    lcnt[m] = (int)e0 + (int)e1;
  }
#pragma unroll
  for (int m = 0; m < 4; ++m)
#pragma unroll
    for (int off = 32; off >= 1; off >>= 1) {
      lmax[m] = fmaxf(lmax[m], __shfl_xor(lmax[m], off));
      lcnt[m] += __shfl_xor(lcnt[m], off);
    }
  if (lane == 0) {
#pragma unroll
    for (int m = 0; m < 4; ++m) { smax[wv][m] = lmax[m]; scnt[wv][m] = lcnt[m]; }
  }
  __syncthreads();
  float mval[4]; bool ne[4];
#pragma unroll
  for (int m = 0; m < 4; ++m) {
    const float mx = fmaxf(fmaxf(smax[0][m], smax[1][m]), fmaxf(smax[2][m], smax[3][m]));
    const int c = scnt[0][m] + scnt[1][m] + scnt[2][m] + scnt[3][m];
    ne[m] = c > 0;
    mval[m] = ne[m] ? mx : 0.f;
  }
  float lsum[4];
#pragma unroll
  for (int m = 0; m < 4; ++m) {
    float s = 0.f;
    if (m0 && n0 == m) s += expf((u0 - mval[m]) / eta[m]);
    if (m1 && n1 == m) s += expf((u1 - mval[m]) / eta[m]);
    lsum[m] = s;
  }
#pragma unroll
  for (int m = 0; m < 4; ++m)
#pragma unroll
    for (int off = 32; off >= 1; off >>= 1) lsum[m] += __shfl_xor(lsum[m], off);
  if (lane == 0) {
#pragma unroll
    for (int m = 0; m < 4; ++m) ssum[wv][m] = lsum[m];
  }
  __syncthreads();
  float sums[4], U[4];
#pragma unroll
  for (int m = 0; m < 4; ++m) {
    const float s = ssum[0][m] + ssum[1][m] + ssum[2][m] + ssum[3][m];
    sums[m] = fmaxf(s, EPSV);
    U[m] = ne[m] ? (mval[m] + eta[m] * logf(sums[m])) : NEGV;
  }
  const float mU = fmaxf(fmaxf(U[0], U[1]), fmaxf(U[2], U[3]));
  float pe[4], pes = 0.f;
#pragma unroll
  for (int m = 0; m < 4; ++m) { pe[m] = expf(U[m] - mU); pes += pe[m]; }
  float pn[4];
#pragma unroll
  for (int m = 0; m < 4; ++m) pn[m] = pe[m] / pes;
  if (tid == 0) {
#pragma unroll
    for (int m = 0; m < 4; ++m) p_nest[(size_t)b * 4 + m] = pn[m];
  }
  float pt[2];
  const float uu[2] = {u0, u1};
  const int nn[2] = {n0, n1};
  const bool mm[2] = {m0, m1};
#pragma unroll
  for (int k = 0; k < 2; ++k) {
    const bool valid = mm[k] && nn[k] >= 0 && nn[k] < 4;
    float mt = 0.f, st = 1.f, pnt = 0.f, et = 1.f;
#pragma unroll
    for (int m = 0; m < 4; ++m)
      if (nn[k] == m) { mt = mval[m]; st = sums[m]; pnt = pn[m]; et = eta[m]; }
    pt[k] = valid ? pnt * expf((uu[k] - mt) / et) / st : 0.f;
  }
  float lp = pt[0] + pt[1];
  int lmk = (int)m0 + (int)m1;
#pragma unroll
  for (int off = 32; off >= 1; off >>= 1) {
    lp += __shfl_xor(lp, off);
    lmk += __shfl_xor(lmk, off);
  }
  if (lane == 0) { sred[wv] = lp; sredi[wv] = lmk; }
  __syncthreads();
  const float sumpt = sred[0] + sred[1] + sred[2] + sred[3];
  const int nmask = sredi[0] + sredi[1] + sredi[2] + sredi[3];
  const bool fallback = (nmask > 0) && (sumpt <= EPSV);
  if (fallback) {
    const float uni = 1.f / (float)(nmask > 0 ? nmask : 1);
    pt[0] = m0 ? uni : pt[0];
    pt[1] = m1 ? uni : pt[1];
  }
  p_task[base + tid] = pt[0];
  p_task[base + 256 + tid] = pt[1];
}

extern "C" void kernel_launch(void* const* d_in, const int* in_sizes, int n_in,
                              void* d_out, int out_size, void* d_ws, size_t ws_size,
                              hipStream_t stream) {
  const float* state = (const float*)d_in[0];
  const float* tf = (const float*)d_in[1];
  const int* nids = (const int*)d_in[2];
  const int* mask = (const int*)d_in[3];
  const float* emb_w = (const float*)d_in[4];
  const float* emb_b = (const float*)d_in[5];
  const float* w1 = (const float*)d_in[6];
  const float* b1 = (const float*)d_in[7];
  const float* w2 = (const float*)d_in[8];
  const float* b2 = (const float*)d_in[9];
  const float* w3 = (const float*)d_in[10];
  const float* b3 = (const float*)d_in[11];
  const float* etas = (const float*)d_in[12];

  float* out = (float*)d_out;
  float* utils_out = out;            // 65536
  float* p_task = out + 65536;       // 65536
  float* p_nest = out + 131072;      // 512

  char* ws = (char*)d_ws;
  unsigned short* W2t = (unsigned short*)ws; ws += 1024ull * 1024 * 2;    // 2 MB
  float* partial = (float*)ws;               ws += 65536ull * 16 * 4;     // 4 MB
  float* W1e = (float*)ws;                   ws += 5 * 1024 * 4;
  float* sb = (float*)ws;                    ws += 128 * 1024 * 4;
  unsigned short* H1 = (unsigned short*)ws;  ws += 65536ull * 1024 * 2;   // 128 MB

  k_prep<<<772, 256, 0, stream>>>(state, w1, b1, emb_w, emb_b, w2, W1e, sb, W2t);
  k_h1<<<4096, 256, 0, stream>>>(tf, sb, W1e, H1);
  k_gemm2<<<1024, 512, 0, stream>>>(H1, W2t, b2, w3, partial);
  k_softmax<<<128, 256, 0, stream>>>(partial, b3, nids, mask, etas,
                                     utils_out, p_task, p_nest);
}

// Round 9
// 184.370 us; speedup vs baseline: 2.1741x; 1.0216x over previous
//
#include <hip/hip_runtime.h>
#include <stdint.h>

#define NEGV -1.0e9f
#define EPSV 1e-12f

typedef __attribute__((ext_vector_type(8))) short bf16x8;
typedef __attribute__((ext_vector_type(4))) float f32x4;

__device__ __forceinline__ unsigned int f2bf(float f) {
  unsigned int u = __builtin_bit_cast(unsigned int, f);
  u = u + 0x7FFFu + ((u >> 16) & 1u);   // round-to-nearest-even
  return u >> 16;
}

// RNE pack of two f32 -> packed bf16x2 in one VALU inst (same bits as f2bf pair;
// inputs are post-relu finite so NaN behavior is irrelevant).
__device__ __forceinline__ unsigned int cvt_pk_bf16(float lo, float hi) {
  unsigned int r;
  asm("v_cvt_pk_bf16_f32 %0, %1, %2" : "=v"(r) : "v"(lo), "v"(hi));
  return r;
}

// ---------------- k_prep: one launch, three independent jobs
__global__ __launch_bounds__(256) void k_prep(
    const float* __restrict__ state, const float* __restrict__ w1,
    const float* __restrict__ b1, const float* __restrict__ emb_w,
    const float* __restrict__ emb_b, const float* __restrict__ w2,
    float* __restrict__ W1e, float* __restrict__ sb,
    unsigned short* __restrict__ W2t) {
  const int blk = blockIdx.x;
  const int tid = threadIdx.x;
  if (blk < 4) {
    const int j = blk * 256 + tid;
    float a0 = 0.f, a1 = 0.f, a2 = 0.f, a3 = 0.f, a4 = 0.f;
    for (int e = 0; e < 256; ++e) {
      const float w = w1[(size_t)(512 + e) * 1024 + j];
      a0 += emb_w[0 * 256 + e] * w;
      a1 += emb_w[1 * 256 + e] * w;
      a2 += emb_w[2 * 256 + e] * w;
      a3 += emb_w[3 * 256 + e] * w;
      a4 += emb_w[4 * 256 + e] * w;
    }
    W1e[0 * 1024 + j] = a0;
    W1e[1 * 1024 + j] = a1;
    W1e[2 * 1024 + j] = a2;
    W1e[3 * 1024 + j] = a3;
    W1e[4 * 1024 + j] = a4;
  } else if (blk < 516) {
    const int blk2 = blk - 4;
    const int b = blk2 >> 2;
    const int j = (blk2 & 3) * 256 + tid;
    float acc = b1[j];
    for (int e = 0; e < 256; ++e)
      acc += emb_b[e] * w1[(size_t)(512 + e) * 1024 + j];
    const float* st = state + (size_t)b * 512;
    for (int s = 0; s < 512; ++s) acc += st[s] * w1[(size_t)s * 1024 + j];
    sb[(size_t)b * 1024 + j] = acc;
  } else {
    __shared__ float tile[64][65];
    const int blk2 = blk - 516;
    const int gn = blk2 & 15, gk = blk2 >> 4;
    const int c = tid & 63, w = tid >> 6;
#pragma unroll
    for (int i = 0; i < 16; ++i) {
      const int r = i * 4 + w;
      tile[r][c] = w2[(size_t)(gk * 64 + r) * 1024 + gn * 64 + c];
    }
    __syncthreads();
#pragma unroll
    for (int i = 0; i < 16; ++i) {
      const int r = i * 4 + w;
      W2t[(size_t)(gn * 64 + r) * 1024 + gk * 64 + c] = (unsigned short)f2bf(tile[c][r]);
    }
  }
}

// ---------------- k_h1: materialize H1 = relu(tf @ W1e + sb) as bf16 [65536][1024].
// 8 rows per thread (W1e regs amortized 8x); writes coalesced 16B.
__global__ __launch_bounds__(256) void k_h1(
    const float* __restrict__ tf, const float* __restrict__ sbm,
    const float* __restrict__ W1em, unsigned short* __restrict__ H1) {
  const int tid = threadIdx.x;
  const int j0 = (tid & 127) << 3;
  const int r0 = (blockIdx.x * 2 + (tid >> 7)) * 8;   // 8 rows per thread
  const int b = r0 >> 9;
  const float* sbp = sbm + (size_t)b * 1024 + j0;
  const float4 sa = *(const float4*)(sbp);
  const float4 sbv = *(const float4*)(sbp + 4);
  float4 wa[5], wb[5];
#pragma unroll
  for (int i = 0; i < 5; ++i) {
    wa[i] = *(const float4*)(W1em + i * 1024 + j0);
    wb[i] = *(const float4*)(W1em + i * 1024 + j0 + 4);
  }
#pragma unroll
  for (int r = 0; r < 8; ++r) {
    const float* f = tf + (size_t)(r0 + r) * 5;
    const float f0 = f[0], f1 = f[1], f2 = f[2], f3 = f[3], f4 = f[4];
    float h0 = fmaf(f4, wa[4].x, fmaf(f3, wa[3].x, fmaf(f2, wa[2].x, fmaf(f1, wa[1].x, fmaf(f0, wa[0].x, sa.x)))));
    float h1 = fmaf(f4, wa[4].y, fmaf(f3, wa[3].y, fmaf(f2, wa[2].y, fmaf(f1, wa[1].y, fmaf(f0, wa[0].y, sa.y)))));
    float h2 = fmaf(f4, wa[4].z, fmaf(f3, wa[3].z, fmaf(f2, wa[2].z, fmaf(f1, wa[1].z, fmaf(f0, wa[0].z, sa.z)))));
    float h3 = fmaf(f4, wa[4].w, fmaf(f3, wa[3].w, fmaf(f2, wa[2].w, fmaf(f1, wa[1].w, fmaf(f0, wa[0].w, sa.w)))));
    float h4 = fmaf(f4, wb[4].x, fmaf(f3, wb[3].x, fmaf(f2, wb[2].x, fmaf(f1, wb[1].x, fmaf(f0, wb[0].x, sbv.x)))));
    float h5 = fmaf(f4, wb[4].y, fmaf(f3, wb[3].y, fmaf(f2, wb[2].y, fmaf(f1, wb[1].y, fmaf(f0, wb[0].y, sbv.y)))));
    float h6 = fmaf(f4, wb[4].z, fmaf(f3, wb[3].z, fmaf(f2, wb[2].z, fmaf(f1, wb[1].z, fmaf(f0, wb[0].z, sbv.z)))));
    float h7 = fmaf(f4, wb[4].w, fmaf(f3, wb[3].w, fmaf(f2, wb[2].w, fmaf(f1, wb[1].w, fmaf(f0, wb[0].w, sbv.w)))));
    h0 = fmaxf(h0, 0.f); h1 = fmaxf(h1, 0.f); h2 = fmaxf(h2, 0.f); h3 = fmaxf(h3, 0.f);
    h4 = fmaxf(h4, 0.f); h5 = fmaxf(h5, 0.f); h6 = fmaxf(h6, 0.f); h7 = fmaxf(h7, 0.f);
    uint4 pk;
    pk.x = cvt_pk_bf16(h0, h1);
    pk.y = cvt_pk_bf16(h2, h3);
    pk.z = cvt_pk_bf16(h4, h5);
    pk.w = cvt_pk_bf16(h6, h7);
    *(uint4*)&H1[(size_t)(r0 + r) * 1024 + j0] = pk;
  }
}

// ---------------- k_gemm2: homogeneous 8-wave 256x256 GEMM (H1 @ W2t) + epilogue.
// R19: R8's 4-phase barrier-pair got only 39.5% MfmaUtil (945 TF). Three
// deviations from the verified m201 schedule, fixed here:
//  1. DROP sched_barrier(0) + explicit lgkmcnt(0) — compiler emits
//     fine-grained lgkmcnt(4/3/1/0) itself (m97 asm); sched_barrier(0)
//     order-pinning is a documented regression (m141: 510 TF).
//  2. A-frag ds_reads ONE PHASE AHEAD in 2 rotating 4-frag slots (B all at
//     tile top) — operand latency hides behind a full barrier-pair + MFMA
//     cluster instead of sitting on the critical path.
//  3. Staging concentrated at p0/p1 (4+4 loads) — the p3 vmcnt(0) then waits
//     on loads >=2 phases (~1000 cyc) old, not same-phase (was full HBM
//     latency exposed per tile).
// Geometry unchanged: 512 thr / 8 waves (2/SIMD), BK=64, 2x64KB LDS dbuf,
// acc 128 AGPR; arch VGPR must stay <=128 (WRITE_SIZE=4096KB no-spill
// sentinel; bank-conflict 0 sentinel).
__global__ __launch_bounds__(512, 2) void k_gemm2(
    const unsigned short* __restrict__ H1, const unsigned short* __restrict__ W2t,
    const float* __restrict__ b2, const float* __restrict__ w3,
    float* __restrict__ partial) {
  __shared__ unsigned short As[2][16384];   // [buf][256 rows][64 k] swizzled
  __shared__ unsigned short Bs[2][16384];

  const int bid = blockIdx.x;
  const int swz = (bid & 7) * 128 + (bid >> 3);   // XCD swizzle (1024 % 8 == 0)
  const int bx = swz >> 2, by = swz & 3;
  const int row0 = bx << 8, col0 = by << 8;

  const int tid = threadIdx.x, lane = tid & 63, wid = tid >> 6;

  // ---- staging addresses (all 8 waves stage both A and B)
  const int sr = (wid << 5) + (lane >> 3);               // tile row; + q*8
  const int scol = (((lane & 7) ^ ((lane >> 3) & 7)) << 3);  // pre-swizzled src chunk
  const size_t abase = (size_t)(row0 + sr) * 1024 + scol;
  const size_t bbase = (size_t)(col0 + sr) * 1024 + scol;
  const int ldsb = (wid << 5) * 64;                      // wave-uniform dest; + q*512

#define STAGE8(kt, d)                                                         \
    _Pragma("unroll")                                                         \
    for (int q = 0; q < 4; ++q) {                                             \
      __builtin_amdgcn_global_load_lds(                                       \
          (const __attribute__((address_space(1))) void*)(                    \
              H1 + abase + (size_t)q * 8192 + (kt) * 64),                     \
          (__attribute__((address_space(3))) void*)(As[d] + ldsb + q * 512),  \
          16, 0, 0);                                                          \
      __builtin_amdgcn_global_load_lds(                                       \
          (const __attribute__((address_space(1))) void*)(                    \
              W2t + bbase + (size_t)q * 8192 + (kt) * 64),                    \
          (__attribute__((address_space(3))) void*)(Bs[d] + ldsb + q * 512),  \
          16, 0, 0);                                                          \
    }

  // 4 loads: q-pairs {2g, 2g+1} of (A,B)
#define STAGE4(kt, d, g)                                                      \
    _Pragma("unroll")                                                         \
    for (int qq = 2 * (g); qq < 2 * (g) + 2; ++qq) {                          \
      __builtin_amdgcn_global_load_lds(                                       \
          (const __attribute__((address_space(1))) void*)(                    \
              H1 + abase + (size_t)qq * 8192 + (kt) * 64),                    \
          (__attribute__((address_space(3))) void*)(As[d] + ldsb + qq * 512), \
          16, 0, 0);                                                          \
      __builtin_amdgcn_global_load_lds(                                       \
          (const __attribute__((address_space(1))) void*)(                    \
              W2t + bbase + (size_t)qq * 8192 + (kt) * 64),                   \
          (__attribute__((address_space(3))) void*)(Bs[d] + ldsb + qq * 512), \
          16, 0, 0);                                                          \
    }

  // ---- consumer-side constants (identical fragment geometry to R7/R8)
  const int wr = wid >> 2, wc = wid & 3;
  const int lm = lane & 15, lg = lane >> 4;
  const int aoff = (wr * 128 + lm) * 64;        // + m*1024 + s{0,1}
  const int boff = (wc * 64 + lm) * 64;         // + n*1024 + s{0,1}
  const int s0 = ((lg ^ (lm & 7)) << 3);        // k16 = lg
  const int s1 = (((4 + lg) ^ (lm & 7)) << 3);  // k16 = 4+lg

  f32x4 acc[8][4];
#pragma unroll
  for (int m = 0; m < 8; ++m)
#pragma unroll
    for (int n = 0; n < 4; ++n) acc[m][n] = (f32x4){0.f, 0.f, 0.f, 0.f};

  // ---- prologue: stage tile 0, full drain
  STAGE8(0, 0);
  __syncthreads();

#pragma unroll 1
  for (int t = 0; t < 16; ++t) {
    const unsigned short* Ad = As[t & 1];
    const unsigned short* Bd = Bs[t & 1];
    bf16x8 bk0[4], bk1[4], aS[2][4];
    // ---- tile-top burst: all 8 B-frags + phase-0 A-frags
#pragma unroll
    for (int n = 0; n < 4; ++n) {
      bk0[n] = *(const bf16x8*)(Bd + boff + n * 1024 + s0);
      bk1[n] = *(const bf16x8*)(Bd + boff + n * 1024 + s1);
    }
    aS[0][0] = *(const bf16x8*)(Ad + aoff + 0 * 1024 + s0);
    aS[0][1] = *(const bf16x8*)(Ad + aoff + 0 * 1024 + s1);
    aS[0][2] = *(const bf16x8*)(Ad + aoff + 1 * 1024 + s0);
    aS[0][3] = *(const bf16x8*)(Ad + aoff + 1 * 1024 + s1);
#pragma unroll
    for (int p = 0; p < 4; ++p) {
      const int cur = p & 1, nxt = cur ^ 1;
      // ---- next phase's A-frags (one phase ahead; compiler emits the
      //      fine-grained lgkm waits at their first MFMA use next phase)
      if (p < 3) {
        aS[nxt][0] = *(const bf16x8*)(Ad + aoff + (2 * p + 2) * 1024 + s0);
        aS[nxt][1] = *(const bf16x8*)(Ad + aoff + (2 * p + 2) * 1024 + s1);
        aS[nxt][2] = *(const bf16x8*)(Ad + aoff + (2 * p + 3) * 1024 + s0);
        aS[nxt][3] = *(const bf16x8*)(Ad + aoff + (2 * p + 3) * 1024 + s1);
      }
      // ---- staging early: 4 loads at p0, 4 at p1 (drain slack >=2 phases)
      if (t < 15 && p < 2) STAGE4(t + 1, (t + 1) & 1, p);
      __builtin_amdgcn_s_barrier();
      __builtin_amdgcn_s_setprio(1);
#pragma unroll
      for (int n = 0; n < 4; ++n)
        acc[2 * p][n] = __builtin_amdgcn_mfma_f32_16x16x32_bf16(aS[cur][0], bk0[n], acc[2 * p][n], 0, 0, 0);
#pragma unroll
      for (int n = 0; n < 4; ++n)
        acc[2 * p][n] = __builtin_amdgcn_mfma_f32_16x16x32_bf16(aS[cur][1], bk1[n], acc[2 * p][n], 0, 0, 0);
#pragma unroll
      for (int n = 0; n < 4; ++n)
        acc[2 * p + 1][n] = __builtin_amdgcn_mfma_f32_16x16x32_bf16(aS[cur][2], bk0[n], acc[2 * p + 1][n], 0, 0, 0);
#pragma unroll
      for (int n = 0; n < 4; ++n)
        acc[2 * p + 1][n] = __builtin_amdgcn_mfma_f32_16x16x32_bf16(aS[cur][3], bk1[n], acc[2 * p + 1][n], 0, 0, 0);
      __builtin_amdgcn_s_setprio(0);
      // ---- tile end: drain own 8 stage loads (issued at p0/p1)
      if (p == 3 && t < 15) asm volatile("s_waitcnt vmcnt(0)" ::: "memory");
      __builtin_amdgcn_s_barrier();
    }
  }
#undef STAGE8
#undef STAGE4

  // ---- epilogue: partial[row][by*4+wc] = sum_cols relu(acc + b2[col]) * w3[col]
  float b2v[4], w3v[4];
#pragma unroll
  for (int n = 0; n < 4; ++n) {
    const int col = col0 + wc * 64 + n * 16 + lm;
    b2v[n] = b2[col];
    w3v[n] = w3[col];
  }
#pragma unroll
  for (int m = 0; m < 8; ++m) {
#pragma unroll
    for (int r = 0; r < 4; ++r) {
      float v = 0.f;
#pragma unroll
      for (int n = 0; n < 4; ++n) {
        float h = acc[m][n][r] + b2v[n];
        h = fmaxf(h, 0.f);
        v += h * w3v[n];
      }
      v += __shfl_xor(v, 1, 16);
      v += __shfl_xor(v, 2, 16);
      v += __shfl_xor(v, 4, 16);
      v += __shfl_xor(v, 8, 16);
      if (lm == 0)
        partial[(size_t)(row0 + wr * 128 + m * 16 + lg * 4 + r) * 16 + by * 4 + wc] = v;
    }
  }
}

// ---------------- k_softmax: fused utils-reduction + nested-logit softmax
__global__ __launch_bounds__(256) void k_softmax(
    const float* __restrict__ partial, const float* __restrict__ b3,
    const int* __restrict__ nids, const int* __restrict__ mask,
    const float* __restrict__ etas, float* __restrict__ utils_out,
    float* __restrict__ p_task, float* __restrict__ p_nest) {
  const int b = blockIdx.x, tid = threadIdx.x;
  const int lane = tid & 63, wv = tid >> 6;
  __shared__ float smax[4][4];
  __shared__ int scnt[4][4];
  __shared__ float ssum[4][4];
  __shared__ float sred[4];
  __shared__ int sredi[4];

  const size_t base = (size_t)b * 512;
  const float b3v = b3[0];
  float uraw[2];
#pragma unroll
  for (int k = 0; k < 2; ++k) {
    const size_t row = base + tid + k * 256;
    const float4* p = (const float4*)(partial + row * 16);
    const float4 pa = p[0], pb = p[1], pc = p[2], pd = p[3];
    uraw[k] = b3v + pa.x + pa.y + pa.z + pa.w + pb.x + pb.y + pb.z + pb.w +
              pc.x + pc.y + pc.z + pc.w + pd.x + pd.y + pd.z + pd.w;
  }
  const int n0 = nids[base + tid], n1 = nids[base + 256 + tid];
  const bool m0 = mask[base + tid] != 0, m1 = mask[base + 256 + tid] != 0;
  const float u0 = m0 ? uraw[0] : NEGV;
  const float u1 = m1 ? uraw[1] : NEGV;
  utils_out[base + tid] = u0;
  utils_out[base + 256 + tid] = u1;
  const float eta[4] = {etas[0], etas[1], etas[2], etas[3]};

  float lmax[4]; int lcnt[4];
#pragma unroll
  for (int m = 0; m < 4; ++m) {
    const bool e0 = m0 && (n0 == m), e1 = m1 && (n1 == m);
    lmax[m] = fmaxf(e0 ? u0 : -INFINITY, e1 ? u1 : -INFINITY);
    lcnt[m] = (int)e0 + (int)e1;
  }
#pragma unroll
  for (int m = 0; m < 4; ++m)
#pragma unroll
    for (int off = 32; off >= 1; off >>= 1) {
      lmax[m] = fmaxf(lmax[m], __shfl_xor(lmax[m], off));
      lcnt[m] += __shfl_xor(lcnt[m], off);
    }
  if (lane == 0) {
#pragma unroll
    for (int m = 0; m < 4; ++m) { smax[wv][m] = lmax[m]; scnt[wv][m] = lcnt[m]; }
  }
  __syncthreads();
  float mval[4]; bool ne[4];
#pragma unroll
  for (int m = 0; m < 4; ++m) {
    const float mx = fmaxf(fmaxf(smax[0][m], smax[1][m]), fmaxf(smax[2][m], smax[3][m]));
    const int c = scnt[0][m] + scnt[1][m] + scnt[2][m] + scnt[3][m];
    ne[m] = c > 0;
    mval[m] = ne[m] ? mx : 0.f;
  }
  float lsum[4];
#pragma unroll
  for (int m = 0; m < 4; ++m) {
    float s = 0.f;
    if (m0 && n0 == m) s += expf((u0 - mval[m]) / eta[m]);
    if (m1 && n1 == m) s += expf((u1 - mval[m]) / eta[m]);
    lsum[m] = s;
  }
#pragma unroll
  for (int m = 0; m < 4; ++m)
#pragma unroll
    for (int off = 32; off >= 1; off >>= 1) lsum[m] += __shfl_xor(lsum[m], off);
  if (lane == 0) {
#pragma unroll
    for (int m = 0; m < 4; ++m) ssum[wv][m] = lsum[m];
  }
  __syncthreads();
  float sums[4], U[4];
#pragma unroll
  for (int m = 0; m < 4; ++m) {
    const float s = ssum[0][m] + ssum[1][m] + ssum[2][m] + ssum[3][m];
    sums[m] = fmaxf(s, EPSV);
    U[m] = ne[m] ? (mval[m] + eta[m] * logf(sums[m])) : NEGV;
  }
  const float mU = fmaxf(fmaxf(U[0], U[1]), fmaxf(U[2], U[3]));
  float pe[4], pes = 0.f;
#pragma unroll
  for (int m = 0; m < 4; ++m) { pe[m] = expf(U[m] - mU); pes += pe[m]; }
  float pn[4];
#pragma unroll
  for (int m = 0; m < 4; ++m) pn[m] = pe[m] / pes;
  if (tid == 0) {
#pragma unroll
    for (int m = 0; m < 4; ++m) p_nest[(size_t)b * 4 + m] = pn[m];
  }
  float pt[2];
  const float uu[2] = {u0, u1};
  const int nn[2] = {n0, n1};
  const bool mm[2] = {m0, m1};
#pragma unroll
  for (int k = 0; k < 2; ++k) {
    const bool valid = mm[k] && nn[k] >= 0 && nn[k] < 4;
    float mt = 0.f, st = 1.f, pnt = 0.f, et = 1.f;
#pragma unroll
    for (int m = 0; m < 4; ++m)
      if (nn[k] == m) { mt = mval[m]; st = sums[m]; pnt = pn[m]; et = eta[m]; }
    pt[k] = valid ? pnt * expf((uu[k] - mt) / et) / st : 0.f;
  }
  float lp = pt[0] + pt[1];
  int lmk = (int)m0 + (int)m1;
#pragma unroll
  for (int off = 32; off >= 1; off >>= 1) {
    lp += __shfl_xor(lp, off);
    lmk += __shfl_xor(lmk, off);
  }
  if (lane == 0) { sred[wv] = lp; sredi[wv] = lmk; }
  __syncthreads();
  const float sumpt = sred[0] + sred[1] + sred[2] + sred[3];
  const int nmask = sredi[0] + sredi[1] + sredi[2] + sredi[3];
  const bool fallback = (nmask > 0) && (sumpt <= EPSV);
  if (fallback) {
    const float uni = 1.f / (float)(nmask > 0 ? nmask : 1);
    pt[0] = m0 ? uni : pt[0];
    pt[1] = m1 ? uni : pt[1];
  }
  p_task[base + tid] = pt[0];
  p_task[base + 256 + tid] = pt[1];
}

extern "C" void kernel_launch(void* const* d_in, const int* in_sizes, int n_in,
                              void* d_out, int out_size, void* d_ws, size_t ws_size,
                              hipStream_t stream) {
  const float* state = (const float*)d_in[0];
  const float* tf = (const float*)d_in[1];
  const int* nids = (const int*)d_in[2];
  const int* mask = (const int*)d_in[3];
  const float* emb_w = (const float*)d_in[4];
  const float* emb_b = (const float*)d_in[5];
  const float* w1 = (const float*)d_in[6];
  const float* b1 = (const float*)d_in[7];
  const float* w2 = (const float*)d_in[8];
  const float* b2 = (const float*)d_in[9];
  const float* w3 = (const float*)d_in[10];
  const float* b3 = (const float*)d_in[11];
  const float* etas = (const float*)d_in[12];

  float* out = (float*)d_out;
  float* utils_out = out;            // 65536
  float* p_task = out + 65536;       // 65536
  float* p_nest = out + 131072;      // 512

  char* ws = (char*)d_ws;
  unsigned short* W2t = (unsigned short*)ws; ws += 1024ull * 1024 * 2;    // 2 MB
  float* partial = (float*)ws;               ws += 65536ull * 16 * 4;     // 4 MB
  float* W1e = (float*)ws;                   ws += 5 * 1024 * 4;
  float* sb = (float*)ws;                    ws += 128 * 1024 * 4;
  unsigned short* H1 = (unsigned short*)ws;  ws += 65536ull * 1024 * 2;   // 128 MB

  k_prep<<<772, 256, 0, stream>>>(state, w1, b1, emb_w, emb_b, w2, W1e, sb, W2t);
  k_h1<<<4096, 256, 0, stream>>>(tf, sb, W1e, H1);
  k_gemm2<<<1024, 512, 0, stream>>>(H1, W2t, b2, w3, partial);
  k_softmax<<<128, 256, 0, stream>>>(partial, b3, nids, mask, etas,
                                     utils_out, p_task, p_nest);
}